// Round 1
// baseline (811.923 us; speedup 1.0000x reference)
//
#include <hip/hip_runtime.h>
#include <hip/hip_bf16.h>

typedef unsigned short u16;
typedef unsigned int   u32;

// ---------- bf16 helpers (bit-exact storage round-trip) ----------
__device__ __forceinline__ float bf2f(u16 u) {
    union { u32 i; float f; } x; x.i = ((u32)u) << 16; return x.f;
}
__device__ __forceinline__ u16 f2bf(float f) {
    union { float f; u32 i; } x; x.f = f;
    u32 i = x.i;
    u32 r = (i + 0x7fffu + ((i >> 16) & 1u)) >> 16;  // round-to-nearest-even
    return (u16)r;
}

// =============== 1. sin/cos tables (4096 x 64), fp64 for accuracy ===========
__global__ void k_tables(float* __restrict__ sinT, float* __restrict__ cosT) {
    int t = blockIdx.x;      // spatial index 0..4095 (h*64+w)
    int j = threadIdx.x;     // dim 0..63
    int i = j >> 1;
    double ang = pow(10000.0, -(double)i / 31.0);
    double a = (double)t * ang;
    sinT[t * 64 + j] = (float)sin(a);
    cosT[t * 64 + j] = (float)cos(a);
}

// =============== 2. QKV projection + bias + k-scale + RoPE ==================
// x: (B=16, C=256, HW=4096) fp32.  Out: token-major (65536, 256) bf16.
// grid (512, 2, 3)  block 256.  Tile: 128 tokens x 128 outcols, K-step 32.
__global__ __launch_bounds__(256) void k_qkv(
    const float* __restrict__ x,
    const float* __restrict__ Wq, const float* __restrict__ bq,
    const float* __restrict__ Wk, const float* __restrict__ bk,
    const float* __restrict__ Wv, const float* __restrict__ bv,
    const float* __restrict__ sinT, const float* __restrict__ cosT,
    u16* __restrict__ qr, u16* __restrict__ kr, u16* __restrict__ vO)
{
    __shared__ float Xs[32][132];   // [cc][token] (transposed for float4 reads)
    __shared__ float Ws[32][128];   // [cc][outcol]

    const int mat = blockIdx.z;
    const float* W    = (mat == 0) ? Wq : (mat == 1) ? Wk : Wv;
    const float* bias = (mat == 0) ? bq : (mat == 1) ? bk : bv;
    u16* out          = (mat == 0) ? qr : (mat == 1) ? kr : vO;

    const int t0 = blockIdx.x * 128;
    const int b  = t0 >> 12;
    const int s0 = t0 & 4095;
    const int o0 = blockIdx.y * 128;
    const int tid = threadIdx.x;
    const int ty = tid >> 4, tx = tid & 15;

    float acc[8][8];
#pragma unroll
    for (int r = 0; r < 8; r++)
#pragma unroll
        for (int u = 0; u < 8; u++) acc[r][u] = 0.f;

    for (int c0 = 0; c0 < 256; c0 += 32) {
#pragma unroll
        for (int qq = 0; qq < 16; ++qq) {
            int idx = qq * 256 + tid;
            int tt = idx & 127, cc = idx >> 7;
            Xs[cc][tt] = x[(size_t)(b * 256 + c0 + cc) * 4096 + s0 + tt];
        }
#pragma unroll
        for (int qq = 0; qq < 16; ++qq) {
            int idx = qq * 256 + tid;
            int oo = idx & 127, cc = idx >> 7;
            Ws[cc][oo] = W[(c0 + cc) * 256 + o0 + oo];
        }
        __syncthreads();
#pragma unroll
        for (int cc = 0; cc < 32; ++cc) {
            float4 a0 = *(const float4*)&Xs[cc][ty * 8];
            float4 a1 = *(const float4*)&Xs[cc][ty * 8 + 4];
            float4 b0 = *(const float4*)&Ws[cc][tx * 8];
            float4 b1 = *(const float4*)&Ws[cc][tx * 8 + 4];
            float av[8] = {a0.x, a0.y, a0.z, a0.w, a1.x, a1.y, a1.z, a1.w};
            float bw[8] = {b0.x, b0.y, b0.z, b0.w, b1.x, b1.y, b1.z, b1.w};
#pragma unroll
            for (int r = 0; r < 8; r++)
#pragma unroll
                for (int u = 0; u < 8; u++) acc[r][u] += av[r] * bw[u];
        }
        __syncthreads();
    }

    const float kscale = (mat == 1) ? 0.125f : 1.0f;
#pragma unroll
    for (int r = 0; r < 8; r++) {
        int tloc = ty * 8 + r;
        int s = s0 + tloc;
        size_t row = (size_t)(t0 + tloc) * 256 + o0 + tx * 8;
        u16 hv[8];
        if (mat == 2) {
#pragma unroll
            for (int u = 0; u < 8; u++)
                hv[u] = f2bf(acc[r][u] + bias[o0 + tx * 8 + u]);
        } else {
            float vr[8];
#pragma unroll
            for (int u = 0; u < 8; u++)
                vr[u] = (acc[r][u] + bias[o0 + tx * 8 + u]) * kscale;
#pragma unroll
            for (int u = 0; u < 8; u += 2) {
                int j = (o0 + tx * 8 + u) & 63;  // dim within head; pairs aligned
                float ce = cosT[s * 64 + j],     se = sinT[s * 64 + j];
                float co = cosT[s * 64 + j + 1], so = sinT[s * 64 + j + 1];
                float e = vr[u], o_ = vr[u + 1];
                hv[u]     = f2bf(e * ce - o_ * se);   // x*cos + rot(x)*sin, even
                hv[u + 1] = f2bf(o_ * co + e * so);   // odd
            }
        }
        *(ushort4*)(out + row)     = *(ushort4*)&hv[0];
        *(ushort4*)(out + row + 4) = *(ushort4*)&hv[4];
    }
}

// =============== 3. LEPE: 5x5 depthwise conv on v (NHWC) ====================
// grid (64 spatial tiles, 4 chan groups, 16 batch)  block 256.
__global__ __launch_bounds__(256) void k_lepe(
    const u16* __restrict__ v, const float* __restrict__ dwk,
    const float* __restrict__ dwb, u16* __restrict__ lepe)
{
    __shared__ float Vh[12][12][64];
    __shared__ float Kl[25][64];
    const int b = blockIdx.z, cg = blockIdx.y * 64;
    const int ty0 = (blockIdx.x >> 3) * 8, tx0 = (blockIdx.x & 7) * 8;
    const int tid = threadIdx.x;

    for (int idx = tid; idx < 1600; idx += 256) {
        int tap = idx >> 6, c = idx & 63;
        Kl[tap][c] = dwk[tap * 256 + cg + c];
    }
#pragma unroll
    for (int qq = 0; qq < 36; ++qq) {
        int idx = qq * 256 + tid;
        int c = idx & 63, p = idx >> 6;   // p 0..143
        int py = p / 12, px = p - py * 12;
        int gy = ty0 + py - 2, gx = tx0 + px - 2;
        float val = 0.f;
        if (gy >= 0 && gy < 64 && gx >= 0 && gx < 64)
            val = bf2f(v[(size_t)(b * 4096 + gy * 64 + gx) * 256 + cg + c]);
        Vh[py][px][c] = val;
    }
    __syncthreads();
    const int c = tid & 63, pg = tid >> 6;
    float kreg[25];
#pragma unroll
    for (int t = 0; t < 25; t++) kreg[t] = Kl[t][c];
    const float bias = dwb[cg + c];
#pragma unroll
    for (int pp = 0; pp < 16; ++pp) {
        int p = pg * 16 + pp;
        int oy = p >> 3, ox = p & 7;
        float a = bias;
#pragma unroll
        for (int dy = 0; dy < 5; ++dy)
#pragma unroll
            for (int dx = 0; dx < 5; ++dx)
                a += Vh[oy + dy][ox + dx][c] * kreg[dy * 5 + dx];
        lepe[(size_t)(b * 4096 + (ty0 + oy) * 64 + tx0 + ox) * 256 + cg + c] = f2bf(a);
    }
}

// =============== 4/5. Axial attention (templated on axis) ===================
// AXIS=0: along W. block=(h,n,b). Q/K/V rows = w, stride 256 in (tok,256).
//         out -> v5T laid out (b,w,n,h,d).
// AXIS=1: along H. block=(w,n,b). Q/K rows = h, stride 64*256. V from v5T
//         (contiguous). out -> attn laid out (b, h*64+w, n*64+d).
template <int AXIS>
__global__ __launch_bounds__(256) void k_attn(
    const u16* __restrict__ qr, const u16* __restrict__ kr,
    const u16* __restrict__ vsrc, u16* __restrict__ outb)
{
    __shared__ float Qs[64][65];   // column (b32) reads, conflict-free
    __shared__ float Ks[64][68];   // row float4 broadcast reads
    __shared__ float Vs[64][68];
    __shared__ float Ps[64][65];
    __shared__ float rmax[4][64], rsum[4][64];

    const int xy = blockIdx.x;
    const int n = blockIdx.y, b = blockIdx.z;
    const int tid = threadIdx.x;

    size_t qbase, vbase; int qstride, vstride;
    if (AXIS == 0) {
        qbase = ((size_t)(b * 4096 + xy * 64)) * 256 + n * 64; qstride = 256;
        vbase = qbase;                                          vstride = 256;
    } else {
        qbase = ((size_t)(b * 4096 + xy)) * 256 + n * 64;       qstride = 64 * 256;
        vbase = ((size_t)((b * 64 + xy) * 4 + n)) * 4096;       vstride = 64;
    }

#pragma unroll
    for (int qq = 0; qq < 4; ++qq) {
        int idx = qq * 256 + tid;        // 0..1023
        int j4 = idx & 15, r = idx >> 4; // row 0..63, 4-elem chunk 0..15
        ushort4 a = *(const ushort4*)(qr + qbase + (size_t)r * qstride + j4 * 4);
        Qs[r][j4 * 4 + 0] = bf2f(a.x); Qs[r][j4 * 4 + 1] = bf2f(a.y);
        Qs[r][j4 * 4 + 2] = bf2f(a.z); Qs[r][j4 * 4 + 3] = bf2f(a.w);
        ushort4 kk = *(const ushort4*)(kr + qbase + (size_t)r * qstride + j4 * 4);
        Ks[r][j4 * 4 + 0] = bf2f(kk.x); Ks[r][j4 * 4 + 1] = bf2f(kk.y);
        Ks[r][j4 * 4 + 2] = bf2f(kk.z); Ks[r][j4 * 4 + 3] = bf2f(kk.w);
        ushort4 vv = *(const ushort4*)(vsrc + vbase + (size_t)r * vstride + j4 * 4);
        Vs[r][j4 * 4 + 0] = bf2f(vv.x); Vs[r][j4 * 4 + 1] = bf2f(vv.y);
        Vs[r][j4 * 4 + 2] = bf2f(vv.z); Vs[r][j4 * 4 + 3] = bf2f(vv.w);
    }
    __syncthreads();

    const int q = tid & 63, part = tid >> 6;
    const float decay = logf(1.0f - exp2f(-(1.0f + 0.75f * (float)n)));

    float sv[16];
#pragma unroll
    for (int u = 0; u < 16; u++) sv[u] = 0.f;
#pragma unroll
    for (int j0 = 0; j0 < 64; j0 += 4) {
        float q0 = Qs[q][j0], q1 = Qs[q][j0 + 1], q2 = Qs[q][j0 + 2], q3 = Qs[q][j0 + 3];
#pragma unroll
        for (int u = 0; u < 16; u++) {
            const float4 kk = *(const float4*)&Ks[part * 16 + u][j0];
            sv[u] += q0 * kk.x + q1 * kk.y + q2 * kk.z + q3 * kk.w;
        }
    }
    float m = -1e30f;
#pragma unroll
    for (int u = 0; u < 16; u++) {
        int col = part * 16 + u;
        sv[u] += fabsf((float)(q - col)) * decay;
        m = fmaxf(m, sv[u]);
    }
    rmax[part][q] = m;
    __syncthreads();
    m = fmaxf(fmaxf(rmax[0][q], rmax[1][q]), fmaxf(rmax[2][q], rmax[3][q]));
    float ssum = 0.f;
#pragma unroll
    for (int u = 0; u < 16; u++) { sv[u] = __expf(sv[u] - m); ssum += sv[u]; }
    rsum[part][q] = ssum;
    __syncthreads();
    ssum = rsum[0][q] + rsum[1][q] + rsum[2][q] + rsum[3][q];
    float rinv = 1.0f / ssum;
#pragma unroll
    for (int u = 0; u < 16; u++) Ps[q][part * 16 + u] = sv[u] * rinv;
    __syncthreads();

    float oa[16];
#pragma unroll
    for (int u = 0; u < 16; u++) oa[u] = 0.f;
#pragma unroll
    for (int k = 0; k < 64; k++) {
        float p = Ps[q][k];
        const float4 v0 = *(const float4*)&Vs[k][part * 16];
        const float4 v1 = *(const float4*)&Vs[k][part * 16 + 4];
        const float4 v2 = *(const float4*)&Vs[k][part * 16 + 8];
        const float4 v3 = *(const float4*)&Vs[k][part * 16 + 12];
        oa[0]  += p * v0.x; oa[1]  += p * v0.y; oa[2]  += p * v0.z; oa[3]  += p * v0.w;
        oa[4]  += p * v1.x; oa[5]  += p * v1.y; oa[6]  += p * v1.z; oa[7]  += p * v1.w;
        oa[8]  += p * v2.x; oa[9]  += p * v2.y; oa[10] += p * v2.z; oa[11] += p * v2.w;
        oa[12] += p * v3.x; oa[13] += p * v3.y; oa[14] += p * v3.z; oa[15] += p * v3.w;
    }
    u16 hv[16];
#pragma unroll
    for (int u = 0; u < 16; u++) hv[u] = f2bf(oa[u]);
    size_t oaddr;
    if (AXIS == 0)  // v5T (b, w=q, n, h=xy, d)
        oaddr = ((size_t)((b * 64 + q) * 4 + n)) * 4096 + xy * 64 + part * 16;
    else            // attn (b, h=q, w=xy, n, d)
        oaddr = ((size_t)(b * 4096 + q * 64 + xy)) * 256 + n * 64 + part * 16;
    *(ushort4*)(outb + oaddr)      = *(ushort4*)&hv[0];
    *(ushort4*)(outb + oaddr + 4)  = *(ushort4*)&hv[4];
    *(ushort4*)(outb + oaddr + 8)  = *(ushort4*)&hv[8];
    *(ushort4*)(outb + oaddr + 12) = *(ushort4*)&hv[12];
}

// =============== 6. (attn + lepe) @ Wo + bo, store NCHW fp32 ================
// grid (512, 2)  block 256.  Tile 128 tokens x 128 outcols, K-step 32.
__global__ __launch_bounds__(256) void k_proj(
    const u16* __restrict__ attn, const u16* __restrict__ lepe,
    const float* __restrict__ Wo, const float* __restrict__ bo,
    float* __restrict__ y)
{
    __shared__ float As[32][132];
    __shared__ float Ws[32][128];
    const int t0 = blockIdx.x * 128;
    const int b = t0 >> 12, s0 = t0 & 4095;
    const int o0 = blockIdx.y * 128;
    const int tid = threadIdx.x;
    const int ty = tid >> 4, tx = tid & 15;

    float acc[8][8];
#pragma unroll
    for (int r = 0; r < 8; r++)
#pragma unroll
        for (int u = 0; u < 8; u++) acc[r][u] = 0.f;

    for (int c0 = 0; c0 < 256; c0 += 32) {
#pragma unroll
        for (int qq = 0; qq < 16; ++qq) {
            int idx = qq * 256 + tid;
            int cc = idx & 31, tt = idx >> 5;
            size_t g = (size_t)(t0 + tt) * 256 + c0 + cc;
            As[cc][tt] = bf2f(attn[g]) + bf2f(lepe[g]);
        }
#pragma unroll
        for (int qq = 0; qq < 16; ++qq) {
            int idx = qq * 256 + tid;
            int oo = idx & 127, cc = idx >> 7;
            Ws[cc][oo] = Wo[(c0 + cc) * 256 + o0 + oo];
        }
        __syncthreads();
#pragma unroll
        for (int cc = 0; cc < 32; ++cc) {
            float4 a0 = *(const float4*)&As[cc][ty * 8];
            float4 a1 = *(const float4*)&As[cc][ty * 8 + 4];
            float4 b0 = *(const float4*)&Ws[cc][tx * 8];
            float4 b1 = *(const float4*)&Ws[cc][tx * 8 + 4];
            float av[8] = {a0.x, a0.y, a0.z, a0.w, a1.x, a1.y, a1.z, a1.w};
            float bw[8] = {b0.x, b0.y, b0.z, b0.w, b1.x, b1.y, b1.z, b1.w};
#pragma unroll
            for (int r = 0; r < 8; r++)
#pragma unroll
                for (int u = 0; u < 8; u++) acc[r][u] += av[r] * bw[u];
        }
        __syncthreads();
    }
#pragma unroll
    for (int u = 0; u < 8; u++) {
        int o = o0 + tx * 8 + u;
        float bb = bo[o];
        float4 w0, w1;
        w0.x = acc[0][u] + bb; w0.y = acc[1][u] + bb;
        w0.z = acc[2][u] + bb; w0.w = acc[3][u] + bb;
        w1.x = acc[4][u] + bb; w1.y = acc[5][u] + bb;
        w1.z = acc[6][u] + bb; w1.w = acc[7][u] + bb;
        float* dst = y + (size_t)(b * 256 + o) * 4096 + s0 + ty * 8;
        *(float4*)dst = w0;
        *(float4*)(dst + 4) = w1;
    }
}

// ============================ launcher ======================================
extern "C" void kernel_launch(void* const* d_in, const int* in_sizes, int n_in,
                              void* d_out, int out_size, void* d_ws, size_t ws_size,
                              hipStream_t stream)
{
    const float* x   = (const float*)d_in[0];
    const float* Wq  = (const float*)d_in[1];
    const float* bq  = (const float*)d_in[2];
    const float* Wk  = (const float*)d_in[3];
    const float* bk  = (const float*)d_in[4];
    const float* Wv  = (const float*)d_in[5];
    const float* bv  = (const float*)d_in[6];
    const float* dwk = (const float*)d_in[7];
    const float* dwb = (const float*)d_in[8];
    const float* Wo  = (const float*)d_in[9];
    const float* bo  = (const float*)d_in[10];
    float* y = (float*)d_out;

    char* ws = (char*)d_ws;
    const size_t MB = 1024 * 1024;
    float* sinT = (float*)(ws);
    float* cosT = (float*)(ws + 1 * MB);
    u16* qr   = (u16*)(ws + 2 * MB);
    u16* kr   = (u16*)(ws + 2 * MB + 1 * 33554432ull);
    u16* v    = (u16*)(ws + 2 * MB + 2 * 33554432ull);
    u16* lepe = (u16*)(ws + 2 * MB + 3 * 33554432ull);
    u16* v5T  = (u16*)(ws + 2 * MB + 4 * 33554432ull);
    u16* attn = v;  // v dead after k_attn<0>; reuse its buffer

    k_tables<<<dim3(4096), dim3(64), 0, stream>>>(sinT, cosT);
    k_qkv<<<dim3(512, 2, 3), dim3(256), 0, stream>>>(
        x, Wq, bq, Wk, bk, Wv, bv, sinT, cosT, qr, kr, v);
    k_lepe<<<dim3(64, 4, 16), dim3(256), 0, stream>>>(v, dwk, dwb, lepe);
    k_attn<0><<<dim3(64, 4, 16), dim3(256), 0, stream>>>(qr, kr, v, v5T);
    k_attn<1><<<dim3(64, 4, 16), dim3(256), 0, stream>>>(qr, kr, v5T, attn);
    k_proj<<<dim3(512, 2), dim3(256), 0, stream>>>(attn, lepe, Wo, bo, y);
}

// Round 2
// 499.223 us; speedup vs baseline: 1.6264x; 1.6264x over previous
//
#include <hip/hip_runtime.h>
#include <hip/hip_bf16.h>

typedef unsigned short u16;
typedef unsigned int   u32;
typedef __attribute__((ext_vector_type(8))) short bf16x8;
typedef __attribute__((ext_vector_type(4))) float f32x4;

// ---------- bf16 helpers ----------
__device__ __forceinline__ float bf2f(u16 u) {
    union { u32 i; float f; } x; x.i = ((u32)u) << 16; return x.f;
}
__device__ __forceinline__ u16 f2bf(float f) {
    union { float f; u32 i; } x; x.f = f;
    u32 i = x.i;
    u32 r = (i + 0x7fffu + ((i >> 16) & 1u)) >> 16;  // RNE
    return (u16)r;
}

// =============== 1. sin/cos tables [4096][32] fp32 (pairs share angle) ======
__global__ void k_tables(float* __restrict__ sinT, float* __restrict__ cosT) {
    int id = blockIdx.x * 256 + threadIdx.x;   // 0..131071 = t*32+i
    int t = id >> 5, i = id & 31;
    double ang = pow(10000.0, -(double)i / 31.0);
    double a = (double)t * ang;
    sinT[id] = (float)sin(a);
    cosT[id] = (float)cos(a);
}

// =============== 2a. weight transpose+convert: WT[out][in] = W[in][out] =====
__global__ __launch_bounds__(256) void k_prep_w(
    const float* __restrict__ Wq, const float* __restrict__ Wk,
    const float* __restrict__ Wv, const float* __restrict__ Wo,
    u16* __restrict__ WTq, u16* __restrict__ WTk,
    u16* __restrict__ WTv, u16* __restrict__ WoT)
{
    __shared__ float T[32][33];
    int z = blockIdx.z;
    const float* W = (z == 0) ? Wq : (z == 1) ? Wk : (z == 2) ? Wv : Wo;
    u16* WT        = (z == 0) ? WTq : (z == 1) ? WTk : (z == 2) ? WTv : WoT;
    int n0 = blockIdx.x * 32, k0 = blockIdx.y * 32;
    int tx = threadIdx.x & 31, ty = threadIdx.x >> 5;   // ty 0..7
#pragma unroll
    for (int i = 0; i < 4; i++)
        T[ty * 4 + i][tx] = W[(k0 + ty * 4 + i) * 256 + n0 + tx];
    __syncthreads();
#pragma unroll
    for (int i = 0; i < 4; i++)
        WT[(n0 + ty * 4 + i) * 256 + k0 + tx] = f2bf(T[tx][ty * 4 + i]);
}

// =============== 2b. x transpose+convert: xT[b*4096+s][c] bf16 ==============
__global__ __launch_bounds__(256) void k_prep_x(
    const float* __restrict__ x, u16* __restrict__ xT)
{
    __shared__ float T[32][33];
    int b = blockIdx.z, c0 = blockIdx.y * 32, s0 = blockIdx.x * 32;
    int tx = threadIdx.x & 31, ty = threadIdx.x >> 5;
#pragma unroll
    for (int i = 0; i < 4; i++)
        T[ty * 4 + i][tx] = x[((size_t)(b * 256 + c0 + ty * 4 + i)) * 4096 + s0 + tx];
    __syncthreads();
#pragma unroll
    for (int i = 0; i < 4; i++)
        xT[((size_t)(b * 4096 + s0 + ty * 4 + i)) * 256 + c0 + tx] = f2bf(T[tx][ty * 4 + i]);
}

// =============== shared MFMA mainloop: 128x128 tile, K=256, BK=64 ===========
// A,B row-major [rows][256] bf16; LDS chunk (r, cc) stored at r*8 + (cc^(r&7))
// (16B chunks). ds_write/ds_read both conflict-free with this swizzle.
__device__ __forceinline__ void gemm_mainloop(
    const u16* __restrict__ Ag, const u16* __restrict__ Bg,
    u16* Alds, u16* Blds, int tid, f32x4 acc[4][4])
{
    const int lane = tid & 63, w = tid >> 6;
    const int wr = w >> 1, wc = w & 1;
    const int l15 = lane & 15, l4 = lane >> 4, l7 = lane & 7;
    const int rb = tid >> 3, cb = tid & 7;       // staging: row-base, chunk-col
    const int sc = cb ^ (rb & 7);                // swizzled chunk col (const/thread)

    bf16x8 as[4], bs[4];
#pragma unroll
    for (int j = 0; j < 4; ++j) {
        as[j] = *(const bf16x8*)(Ag + (size_t)(j * 32 + rb) * 256 + cb * 8);
        bs[j] = *(const bf16x8*)(Bg + (size_t)(j * 32 + rb) * 256 + cb * 8);
    }
#pragma unroll
    for (int ks = 0; ks < 4; ++ks) {
        __syncthreads();                          // prior LDS reads done
#pragma unroll
        for (int j = 0; j < 4; ++j) {
            *(bf16x8*)(Alds + (size_t)(j * 32 + rb) * 64 + sc * 8) = as[j];
            *(bf16x8*)(Blds + (size_t)(j * 32 + rb) * 64 + sc * 8) = bs[j];
        }
        if (ks < 3) {
#pragma unroll
            for (int j = 0; j < 4; ++j) {
                as[j] = *(const bf16x8*)(Ag + (size_t)(j * 32 + rb) * 256 + (ks + 1) * 64 + cb * 8);
                bs[j] = *(const bf16x8*)(Bg + (size_t)(j * 32 + rb) * 256 + (ks + 1) * 64 + cb * 8);
            }
        }
        __syncthreads();
#pragma unroll
        for (int kk = 0; kk < 2; ++kk) {
            bf16x8 af[4], bfr[4];
#pragma unroll
            for (int mi = 0; mi < 4; ++mi) {
                int r = wr * 64 + mi * 16 + l15;
                af[mi] = *(const bf16x8*)(Alds + r * 64 + (((kk * 4 + l4) ^ l7)) * 8);
            }
#pragma unroll
            for (int ni = 0; ni < 4; ++ni) {
                int r = wc * 64 + ni * 16 + l15;
                bfr[ni] = *(const bf16x8*)(Blds + r * 64 + (((kk * 4 + l4) ^ l7)) * 8);
            }
#pragma unroll
            for (int mi = 0; mi < 4; ++mi)
#pragma unroll
                for (int ni = 0; ni < 4; ++ni)
                    acc[mi][ni] = __builtin_amdgcn_mfma_f32_16x16x32_bf16(
                        af[mi], bfr[ni], acc[mi][ni], 0, 0, 0);
        }
    }
}

// =============== 3. QKV projection (MFMA) + bias + k-scale + RoPE ===========
// grid (512 t-blocks, 2 o-blocks, 3 mats), block 256.
__global__ __launch_bounds__(256) void k_qkv_mfma(
    const u16* __restrict__ xT,
    const u16* __restrict__ WTq, const u16* __restrict__ WTk, const u16* __restrict__ WTv,
    const float* __restrict__ bq, const float* __restrict__ bk, const float* __restrict__ bv,
    const float* __restrict__ sinT, const float* __restrict__ cosT,
    u16* __restrict__ qr, u16* __restrict__ kr, u16* __restrict__ vO)
{
    __shared__ alignas(16) u16 Alds[128 * 64];
    __shared__ alignas(16) u16 Blds[128 * 64];

    const int mat = blockIdx.z;
    const u16* WT     = (mat == 0) ? WTq : (mat == 1) ? WTk : WTv;
    const float* bias = (mat == 0) ? bq : (mat == 1) ? bk : bv;
    u16* out          = (mat == 0) ? qr : (mat == 1) ? kr : vO;

    const int t0 = blockIdx.x * 128;
    const int o0 = blockIdx.y * 128;
    const int tid = threadIdx.x;

    f32x4 acc[4][4];
#pragma unroll
    for (int mi = 0; mi < 4; mi++)
#pragma unroll
        for (int ni = 0; ni < 4; ni++) acc[mi][ni] = (f32x4)0.f;

    gemm_mainloop(xT + (size_t)t0 * 256, WT + (size_t)o0 * 256, Alds, Blds, tid, acc);

    const int lane = tid & 63, w = tid >> 6, wr = w >> 1, wc = w & 1;
    const int l15 = lane & 15, l4 = lane >> 4;
    float bcol[4]; int ip[4];
#pragma unroll
    for (int ni = 0; ni < 4; ni++) {
        bcol[ni] = bias[o0 + wc * 64 + ni * 16 + l15];
        ip[ni] = (ni * 16 + l15) >> 1;
    }
    const float kscale = (mat == 1) ? 0.125f : 1.0f;
    const int srow0 = (t0 & 4095) + wr * 64;

#pragma unroll
    for (int mi = 0; mi < 4; mi++) {
#pragma unroll
        for (int rg = 0; rg < 4; rg++) {
            int s = srow0 + mi * 16 + l4 * 4 + rg;            // spatial idx for RoPE
            size_t trow = (size_t)(t0 + wr * 64 + mi * 16 + l4 * 4 + rg) * 256;
#pragma unroll
            for (int ni = 0; ni < 4; ni++) {
                float val = acc[mi][ni][rg] + bcol[ni];
                float res;
                if (mat != 2) {
                    val *= kscale;
                    float prt = __shfl_xor(val, 1);
                    float sv = sinT[s * 32 + ip[ni]];
                    float cv = cosT[s * 32 + ip[ni]];
                    res = (lane & 1) ? (val * cv + prt * sv) : (val * cv - prt * sv);
                } else {
                    res = val;
                }
                float res2 = __shfl_xor(res, 1);
                if (!(lane & 1)) {
                    int o = o0 + wc * 64 + ni * 16 + l15;     // even
                    *(u32*)(out + trow + o) = (u32)f2bf(res) | ((u32)f2bf(res2) << 16);
                }
            }
        }
    }
}

// =============== 4. LEPE: 5x5 depthwise conv on v (NHWC) ====================
__global__ __launch_bounds__(256) void k_lepe(
    const u16* __restrict__ v, const float* __restrict__ dwk,
    const float* __restrict__ dwb, u16* __restrict__ lepe)
{
    __shared__ float Vh[12][12][64];
    __shared__ float Kl[25][64];
    const int b = blockIdx.z, cg = blockIdx.y * 64;
    const int ty0 = (blockIdx.x >> 3) * 8, tx0 = (blockIdx.x & 7) * 8;
    const int tid = threadIdx.x;

    for (int idx = tid; idx < 1600; idx += 256) {
        int tap = idx >> 6, c = idx & 63;
        Kl[tap][c] = dwk[tap * 256 + cg + c];
    }
#pragma unroll
    for (int qq = 0; qq < 36; ++qq) {
        int idx = qq * 256 + tid;
        int c = idx & 63, p = idx >> 6;
        int py = p / 12, px = p - py * 12;
        int gy = ty0 + py - 2, gx = tx0 + px - 2;
        float val = 0.f;
        if (gy >= 0 && gy < 64 && gx >= 0 && gx < 64)
            val = bf2f(v[(size_t)(b * 4096 + gy * 64 + gx) * 256 + cg + c]);
        Vh[py][px][c] = val;
    }
    __syncthreads();
    const int c = tid & 63, pg = tid >> 6;
    float kreg[25];
#pragma unroll
    for (int t = 0; t < 25; t++) kreg[t] = Kl[t][c];
    const float bias = dwb[cg + c];
#pragma unroll
    for (int pp = 0; pp < 16; ++pp) {
        int p = pg * 16 + pp;
        int oy = p >> 3, ox = p & 7;
        float a = bias;
#pragma unroll
        for (int dy = 0; dy < 5; ++dy)
#pragma unroll
            for (int dx = 0; dx < 5; ++dx)
                a += Vh[oy + dy][ox + dx][c] * kreg[dy * 5 + dx];
        lepe[(size_t)(b * 4096 + (ty0 + oy) * 64 + tx0 + ox) * 256 + cg + c] = f2bf(a);
    }
}

// =============== 5/6. Axial attention (AXIS=1 fuses +lepe) ==================
template <int AXIS>
__global__ __launch_bounds__(256) void k_attn(
    const u16* __restrict__ qr, const u16* __restrict__ kr,
    const u16* __restrict__ vsrc, const u16* __restrict__ lepeP,
    u16* __restrict__ outb)
{
    __shared__ float Qs[64][65];
    __shared__ float Ks[64][68];
    __shared__ float Vs[64][68];
    __shared__ float Ps[64][65];
    __shared__ float rmax[4][64], rsum[4][64];

    const int xy = blockIdx.x;
    const int n = blockIdx.y, b = blockIdx.z;
    const int tid = threadIdx.x;

    size_t qbase, vbase; int qstride, vstride;
    if (AXIS == 0) {
        qbase = ((size_t)(b * 4096 + xy * 64)) * 256 + n * 64; qstride = 256;
        vbase = qbase;                                          vstride = 256;
    } else {
        qbase = ((size_t)(b * 4096 + xy)) * 256 + n * 64;       qstride = 64 * 256;
        vbase = ((size_t)((b * 64 + xy) * 4 + n)) * 4096;       vstride = 64;
    }

#pragma unroll
    for (int qq = 0; qq < 4; ++qq) {
        int idx = qq * 256 + tid;
        int j4 = idx & 15, r = idx >> 4;
        ushort4 a = *(const ushort4*)(qr + qbase + (size_t)r * qstride + j4 * 4);
        Qs[r][j4 * 4 + 0] = bf2f(a.x); Qs[r][j4 * 4 + 1] = bf2f(a.y);
        Qs[r][j4 * 4 + 2] = bf2f(a.z); Qs[r][j4 * 4 + 3] = bf2f(a.w);
        ushort4 kk = *(const ushort4*)(kr + qbase + (size_t)r * qstride + j4 * 4);
        Ks[r][j4 * 4 + 0] = bf2f(kk.x); Ks[r][j4 * 4 + 1] = bf2f(kk.y);
        Ks[r][j4 * 4 + 2] = bf2f(kk.z); Ks[r][j4 * 4 + 3] = bf2f(kk.w);
        ushort4 vv = *(const ushort4*)(vsrc + vbase + (size_t)r * vstride + j4 * 4);
        Vs[r][j4 * 4 + 0] = bf2f(vv.x); Vs[r][j4 * 4 + 1] = bf2f(vv.y);
        Vs[r][j4 * 4 + 2] = bf2f(vv.z); Vs[r][j4 * 4 + 3] = bf2f(vv.w);
    }
    __syncthreads();

    const int q = tid & 63, part = tid >> 6;
    const float decay = logf(1.0f - exp2f(-(1.0f + 0.75f * (float)n)));

    float sv[16];
#pragma unroll
    for (int u = 0; u < 16; u++) sv[u] = 0.f;
#pragma unroll
    for (int j0 = 0; j0 < 64; j0 += 4) {
        float q0 = Qs[q][j0], q1 = Qs[q][j0 + 1], q2 = Qs[q][j0 + 2], q3 = Qs[q][j0 + 3];
#pragma unroll
        for (int u = 0; u < 16; u++) {
            const float4 kk = *(const float4*)&Ks[part * 16 + u][j0];
            sv[u] += q0 * kk.x + q1 * kk.y + q2 * kk.z + q3 * kk.w;
        }
    }
    float m = -1e30f;
#pragma unroll
    for (int u = 0; u < 16; u++) {
        int col = part * 16 + u;
        sv[u] += fabsf((float)(q - col)) * decay;
        m = fmaxf(m, sv[u]);
    }
    rmax[part][q] = m;
    __syncthreads();
    m = fmaxf(fmaxf(rmax[0][q], rmax[1][q]), fmaxf(rmax[2][q], rmax[3][q]));
    float ssum = 0.f;
#pragma unroll
    for (int u = 0; u < 16; u++) { sv[u] = __expf(sv[u] - m); ssum += sv[u]; }
    rsum[part][q] = ssum;
    __syncthreads();
    ssum = rsum[0][q] + rsum[1][q] + rsum[2][q] + rsum[3][q];
    float rinv = 1.0f / ssum;
#pragma unroll
    for (int u = 0; u < 16; u++) Ps[q][part * 16 + u] = sv[u] * rinv;
    __syncthreads();

    float oa[16];
#pragma unroll
    for (int u = 0; u < 16; u++) oa[u] = 0.f;
#pragma unroll
    for (int k = 0; k < 64; k++) {
        float p = Ps[q][k];
        const float4 v0 = *(const float4*)&Vs[k][part * 16];
        const float4 v1 = *(const float4*)&Vs[k][part * 16 + 4];
        const float4 v2 = *(const float4*)&Vs[k][part * 16 + 8];
        const float4 v3 = *(const float4*)&Vs[k][part * 16 + 12];
        oa[0]  += p * v0.x; oa[1]  += p * v0.y; oa[2]  += p * v0.z; oa[3]  += p * v0.w;
        oa[4]  += p * v1.x; oa[5]  += p * v1.y; oa[6]  += p * v1.z; oa[7]  += p * v1.w;
        oa[8]  += p * v2.x; oa[9]  += p * v2.y; oa[10] += p * v2.z; oa[11] += p * v2.w;
        oa[12] += p * v3.x; oa[13] += p * v3.y; oa[14] += p * v3.z; oa[15] += p * v3.w;
    }
    size_t oaddr;
    if (AXIS == 0)
        oaddr = ((size_t)((b * 64 + q) * 4 + n)) * 4096 + xy * 64 + part * 16;
    else
        oaddr = ((size_t)(b * 4096 + q * 64 + xy)) * 256 + n * 64 + part * 16;

    if (AXIS == 1) {   // fuse + lepe (same token-major layout)
#pragma unroll
        for (int u2 = 0; u2 < 16; u2 += 4) {
            ushort4 lp = *(const ushort4*)(lepeP + oaddr + u2);
            oa[u2 + 0] += bf2f(lp.x); oa[u2 + 1] += bf2f(lp.y);
            oa[u2 + 2] += bf2f(lp.z); oa[u2 + 3] += bf2f(lp.w);
        }
    }
    u16 hv[16];
#pragma unroll
    for (int u = 0; u < 16; u++) hv[u] = f2bf(oa[u]);
    *(ushort4*)(outb + oaddr)      = *(ushort4*)&hv[0];
    *(ushort4*)(outb + oaddr + 4)  = *(ushort4*)&hv[4];
    *(ushort4*)(outb + oaddr + 8)  = *(ushort4*)&hv[8];
    *(ushort4*)(outb + oaddr + 12) = *(ushort4*)&hv[12];
}

// =============== 7. output projection (MFMA, transposed orient) =============
// D[o][t] = sum_k WoT[o][k] * attnL[t][k]  ->  y NCHW fp32, coalesced stores.
// grid (512 t-blocks, 2 o-blocks), block 256.
__global__ __launch_bounds__(256) void k_proj_mfma(
    const u16* __restrict__ WoT, const u16* __restrict__ attnL,
    const float* __restrict__ bo, float* __restrict__ y)
{
    __shared__ alignas(16) u16 Alds[128 * 64];
    __shared__ alignas(16) u16 Blds[128 * 64];

    const int t0 = blockIdx.x * 128;
    const int o0 = blockIdx.y * 128;
    const int tid = threadIdx.x;

    f32x4 acc[4][4];
#pragma unroll
    for (int mi = 0; mi < 4; mi++)
#pragma unroll
        for (int ni = 0; ni < 4; ni++) acc[mi][ni] = (f32x4)0.f;

    gemm_mainloop(WoT + (size_t)o0 * 256, attnL + (size_t)t0 * 256, Alds, Blds, tid, acc);

    const int lane = tid & 63, w = tid >> 6, wr = w >> 1, wc = w & 1;
    const int l15 = lane & 15, l4 = lane >> 4;
    const int b = t0 >> 12, sb = t0 & 4095;

#pragma unroll
    for (int mi = 0; mi < 4; mi++) {
#pragma unroll
        for (int rg = 0; rg < 4; rg++) {
            int o = o0 + wr * 64 + mi * 16 + l4 * 4 + rg;
            float bb = bo[o];
            float* yrow = y + ((size_t)(b * 256 + o)) * 4096 + sb + wc * 64;
#pragma unroll
            for (int ni = 0; ni < 4; ni++)
                yrow[ni * 16 + l15] = acc[mi][ni][rg] + bb;
        }
    }
}

// ============================ launcher ======================================
extern "C" void kernel_launch(void* const* d_in, const int* in_sizes, int n_in,
                              void* d_out, int out_size, void* d_ws, size_t ws_size,
                              hipStream_t stream)
{
    const float* x   = (const float*)d_in[0];
    const float* Wq  = (const float*)d_in[1];
    const float* bq  = (const float*)d_in[2];
    const float* Wk  = (const float*)d_in[3];
    const float* bk  = (const float*)d_in[4];
    const float* Wv  = (const float*)d_in[5];
    const float* bv  = (const float*)d_in[6];
    const float* dwk = (const float*)d_in[7];
    const float* dwb = (const float*)d_in[8];
    const float* Wo  = (const float*)d_in[9];
    const float* bo  = (const float*)d_in[10];
    float* y = (float*)d_out;

    char* ws = (char*)d_ws;
    const size_t MB = 1024 * 1024;
    float* sinT = (float*)(ws);                      // 512 KB  [4096][32]
    float* cosT = (float*)(ws + 512 * 1024);         // 512 KB
    u16* WTq = (u16*)(ws + 1 * MB);                  // 4 x 128 KB
    u16* WTk = WTq + 65536;
    u16* WTv = WTk + 65536;
    u16* WoT = WTv + 65536;
    u16* qr   = (u16*)(ws + 2 * MB);                 // 32 MB each
    u16* kr   = (u16*)(ws + 2 * MB + 32 * MB);
    u16* v    = (u16*)(ws + 2 * MB + 64 * MB);
    u16* lepe = (u16*)(ws + 2 * MB + 96 * MB);
    u16* xT   = (u16*)(ws + 2 * MB + 128 * MB);      // dead after k_qkv_mfma
    u16* v5T  = xT;                                   // reuse
    u16* attn = v;                                    // reuse (holds attn+lepe)

    k_tables<<<dim3(512), dim3(256), 0, stream>>>(sinT, cosT);
    k_prep_w<<<dim3(8, 8, 4), dim3(256), 0, stream>>>(Wq, Wk, Wv, Wo, WTq, WTk, WTv, WoT);
    k_prep_x<<<dim3(128, 8, 16), dim3(256), 0, stream>>>(x, xT);
    k_qkv_mfma<<<dim3(512, 2, 3), dim3(256), 0, stream>>>(
        xT, WTq, WTk, WTv, bq, bk, bv, sinT, cosT, qr, kr, v);
    k_lepe<<<dim3(64, 4, 16), dim3(256), 0, stream>>>(v, dwk, dwb, lepe);
    k_attn<0><<<dim3(64, 4, 16), dim3(256), 0, stream>>>(qr, kr, v, nullptr, v5T);
    k_attn<1><<<dim3(64, 4, 16), dim3(256), 0, stream>>>(qr, kr, v5T, lepe, attn);
    k_proj_mfma<<<dim3(512, 2), dim3(256), 0, stream>>>(WoT, attn, bo, y);
}

// Round 3
// 326.753 us; speedup vs baseline: 2.4848x; 1.5278x over previous
//
#include <hip/hip_runtime.h>
#include <hip/hip_bf16.h>

typedef unsigned short u16;
typedef unsigned int   u32;
typedef __attribute__((ext_vector_type(8))) short bf16x8;
typedef __attribute__((ext_vector_type(4))) float f32x4;

// ---------- bf16 helpers ----------
__device__ __forceinline__ float bf2f(u16 u) {
    union { u32 i; float f; } x; x.i = ((u32)u) << 16; return x.f;
}
__device__ __forceinline__ u16 f2bf(float f) {
    union { float f; u32 i; } x; x.f = f;
    u32 i = x.i;
    u32 r = (i + 0x7fffu + ((i >> 16) & 1u)) >> 16;  // RNE
    return (u16)r;
}

// =============== 1. sin/cos tables [4096][32] fp32 (pairs share angle) ======
__global__ void k_tables(float* __restrict__ sinT, float* __restrict__ cosT) {
    int id = blockIdx.x * 256 + threadIdx.x;   // 0..131071 = t*32+i
    int t = id >> 5, i = id & 31;
    double ang = pow(10000.0, -(double)i / 31.0);
    double a = (double)t * ang;
    sinT[id] = (float)sin(a);
    cosT[id] = (float)cos(a);
}

// =============== 2a. weight transpose+convert: WT[out][in] = W[in][out] =====
__global__ __launch_bounds__(256) void k_prep_w(
    const float* __restrict__ Wq, const float* __restrict__ Wk,
    const float* __restrict__ Wv, const float* __restrict__ Wo,
    u16* __restrict__ WTq, u16* __restrict__ WTk,
    u16* __restrict__ WTv, u16* __restrict__ WoT)
{
    __shared__ float T[32][33];
    int z = blockIdx.z;
    const float* W = (z == 0) ? Wq : (z == 1) ? Wk : (z == 2) ? Wv : Wo;
    u16* WT        = (z == 0) ? WTq : (z == 1) ? WTk : (z == 2) ? WTv : WoT;
    int n0 = blockIdx.x * 32, k0 = blockIdx.y * 32;
    int tx = threadIdx.x & 31, ty = threadIdx.x >> 5;   // ty 0..7
#pragma unroll
    for (int i = 0; i < 4; i++)
        T[ty * 4 + i][tx] = W[(k0 + ty * 4 + i) * 256 + n0 + tx];
    __syncthreads();
#pragma unroll
    for (int i = 0; i < 4; i++)
        WT[(n0 + ty * 4 + i) * 256 + k0 + tx] = f2bf(T[tx][ty * 4 + i]);
}

// =============== 2b. x transpose+convert: xT[b*4096+s][c] bf16 ==============
__global__ __launch_bounds__(256) void k_prep_x(
    const float* __restrict__ x, u16* __restrict__ xT)
{
    __shared__ float T[32][33];
    int b = blockIdx.z, c0 = blockIdx.y * 32, s0 = blockIdx.x * 32;
    int tx = threadIdx.x & 31, ty = threadIdx.x >> 5;
#pragma unroll
    for (int i = 0; i < 4; i++)
        T[ty * 4 + i][tx] = x[((size_t)(b * 256 + c0 + ty * 4 + i)) * 4096 + s0 + tx];
    __syncthreads();
#pragma unroll
    for (int i = 0; i < 4; i++)
        xT[((size_t)(b * 4096 + s0 + ty * 4 + i)) * 256 + c0 + tx] = f2bf(T[tx][ty * 4 + i]);
}

// =============== shared MFMA mainloop: 128x128 tile, K=256, BK=64 ===========
__device__ __forceinline__ void gemm_mainloop(
    const u16* __restrict__ Ag, const u16* __restrict__ Bg,
    u16* Alds, u16* Blds, int tid, f32x4 acc[4][4])
{
    const int lane = tid & 63, w = tid >> 6;
    const int wr = w >> 1, wc = w & 1;
    const int l15 = lane & 15, l4 = lane >> 4, l7 = lane & 7;
    const int rb = tid >> 3, cb = tid & 7;       // staging: row-base, chunk-col
    const int sc = cb ^ (rb & 7);                // swizzled chunk col

    bf16x8 as[4], bs[4];
#pragma unroll
    for (int j = 0; j < 4; ++j) {
        as[j] = *(const bf16x8*)(Ag + (size_t)(j * 32 + rb) * 256 + cb * 8);
        bs[j] = *(const bf16x8*)(Bg + (size_t)(j * 32 + rb) * 256 + cb * 8);
    }
#pragma unroll
    for (int ks = 0; ks < 4; ++ks) {
        __syncthreads();
#pragma unroll
        for (int j = 0; j < 4; ++j) {
            *(bf16x8*)(Alds + (size_t)(j * 32 + rb) * 64 + sc * 8) = as[j];
            *(bf16x8*)(Blds + (size_t)(j * 32 + rb) * 64 + sc * 8) = bs[j];
        }
        if (ks < 3) {
#pragma unroll
            for (int j = 0; j < 4; ++j) {
                as[j] = *(const bf16x8*)(Ag + (size_t)(j * 32 + rb) * 256 + (ks + 1) * 64 + cb * 8);
                bs[j] = *(const bf16x8*)(Bg + (size_t)(j * 32 + rb) * 256 + (ks + 1) * 64 + cb * 8);
            }
        }
        __syncthreads();
#pragma unroll
        for (int kk = 0; kk < 2; ++kk) {
            bf16x8 af[4], bfr[4];
#pragma unroll
            for (int mi = 0; mi < 4; ++mi) {
                int r = wr * 64 + mi * 16 + l15;
                af[mi] = *(const bf16x8*)(Alds + r * 64 + (((kk * 4 + l4) ^ l7)) * 8);
            }
#pragma unroll
            for (int ni = 0; ni < 4; ++ni) {
                int r = wc * 64 + ni * 16 + l15;
                bfr[ni] = *(const bf16x8*)(Blds + r * 64 + (((kk * 4 + l4) ^ l7)) * 8);
            }
#pragma unroll
            for (int mi = 0; mi < 4; ++mi)
#pragma unroll
                for (int ni = 0; ni < 4; ++ni)
                    acc[mi][ni] = __builtin_amdgcn_mfma_f32_16x16x32_bf16(
                        af[mi], bfr[ni], acc[mi][ni], 0, 0, 0);
        }
    }
}

// =============== 3. QKV projection (MFMA) + bias + k-scale + RoPE ===========
__global__ __launch_bounds__(256) void k_qkv_mfma(
    const u16* __restrict__ xT,
    const u16* __restrict__ WTq, const u16* __restrict__ WTk, const u16* __restrict__ WTv,
    const float* __restrict__ bq, const float* __restrict__ bk, const float* __restrict__ bv,
    const float* __restrict__ sinT, const float* __restrict__ cosT,
    u16* __restrict__ qr, u16* __restrict__ kr, u16* __restrict__ vO)
{
    __shared__ alignas(16) u16 Alds[128 * 64];
    __shared__ alignas(16) u16 Blds[128 * 64];

    const int mat = blockIdx.z;
    const u16* WT     = (mat == 0) ? WTq : (mat == 1) ? WTk : WTv;
    const float* bias = (mat == 0) ? bq : (mat == 1) ? bk : bv;
    u16* out          = (mat == 0) ? qr : (mat == 1) ? kr : vO;

    const int t0 = blockIdx.x * 128;
    const int o0 = blockIdx.y * 128;
    const int tid = threadIdx.x;

    f32x4 acc[4][4];
#pragma unroll
    for (int mi = 0; mi < 4; mi++)
#pragma unroll
        for (int ni = 0; ni < 4; ni++) acc[mi][ni] = (f32x4)0.f;

    gemm_mainloop(xT + (size_t)t0 * 256, WT + (size_t)o0 * 256, Alds, Blds, tid, acc);

    const int lane = tid & 63, w = tid >> 6, wr = w >> 1, wc = w & 1;
    const int l15 = lane & 15, l4 = lane >> 4;
    float bcol[4]; int ip[4];
#pragma unroll
    for (int ni = 0; ni < 4; ni++) {
        bcol[ni] = bias[o0 + wc * 64 + ni * 16 + l15];
        ip[ni] = (ni * 16 + l15) >> 1;
    }
    const float kscale = (mat == 1) ? 0.125f : 1.0f;
    const int srow0 = (t0 & 4095) + wr * 64;

#pragma unroll
    for (int mi = 0; mi < 4; mi++) {
#pragma unroll
        for (int rg = 0; rg < 4; rg++) {
            int s = srow0 + mi * 16 + l4 * 4 + rg;
            size_t trow = (size_t)(t0 + wr * 64 + mi * 16 + l4 * 4 + rg) * 256;
#pragma unroll
            for (int ni = 0; ni < 4; ni++) {
                float val = acc[mi][ni][rg] + bcol[ni];
                float res;
                if (mat != 2) {
                    val *= kscale;
                    float prt = __shfl_xor(val, 1);
                    float sv = sinT[s * 32 + ip[ni]];
                    float cv = cosT[s * 32 + ip[ni]];
                    res = (lane & 1) ? (val * cv + prt * sv) : (val * cv - prt * sv);
                } else {
                    res = val;
                }
                float res2 = __shfl_xor(res, 1);
                if (!(lane & 1)) {
                    int o = o0 + wc * 64 + ni * 16 + l15;
                    *(u32*)(out + trow + o) = (u32)f2bf(res) | ((u32)f2bf(res2) << 16);
                }
            }
        }
    }
}

// =============== 4. LEPE: 5x5 depthwise conv on v (NHWC) ====================
__global__ __launch_bounds__(256) void k_lepe(
    const u16* __restrict__ v, const float* __restrict__ dwk,
    const float* __restrict__ dwb, u16* __restrict__ lepe)
{
    __shared__ float Vh[12][12][64];
    __shared__ float Kl[25][64];
    const int b = blockIdx.z, cg = blockIdx.y * 64;
    const int ty0 = (blockIdx.x >> 3) * 8, tx0 = (blockIdx.x & 7) * 8;
    const int tid = threadIdx.x;

    for (int idx = tid; idx < 1600; idx += 256) {
        int tap = idx >> 6, c = idx & 63;
        Kl[tap][c] = dwk[tap * 256 + cg + c];
    }
#pragma unroll
    for (int qq = 0; qq < 36; ++qq) {
        int idx = qq * 256 + tid;
        int c = idx & 63, p = idx >> 6;
        int py = p / 12, px = p - py * 12;
        int gy = ty0 + py - 2, gx = tx0 + px - 2;
        float val = 0.f;
        if (gy >= 0 && gy < 64 && gx >= 0 && gx < 64)
            val = bf2f(v[(size_t)(b * 4096 + gy * 64 + gx) * 256 + cg + c]);
        Vh[py][px][c] = val;
    }
    __syncthreads();
    const int c = tid & 63, pg = tid >> 6;
    float kreg[25];
#pragma unroll
    for (int t = 0; t < 25; t++) kreg[t] = Kl[t][c];
    const float bias = dwb[cg + c];
#pragma unroll
    for (int pp = 0; pp < 16; ++pp) {
        int p = pg * 16 + pp;
        int oy = p >> 3, ox = p & 7;
        float a = bias;
#pragma unroll
        for (int dy = 0; dy < 5; ++dy)
#pragma unroll
            for (int dx = 0; dx < 5; ++dx)
                a += Vh[oy + dy][ox + dx][c] * kreg[dy * 5 + dx];
        lepe[(size_t)(b * 4096 + (ty0 + oy) * 64 + tx0 + ox) * 256 + cg + c] = f2bf(a);
    }
}

// =============== 5/6. Axial attention, per-wave MFMA flash ==================
// One wave per (b, line, head). AXIS=0: along W (v token-major in, v5 out
// as (b,w,n,h,d)). AXIS=1: along H (v5 rows contiguous in, token-major out,
// fused +lepe).
template <int AXIS>
__global__ __launch_bounds__(256) void k_attn_mfma(
    const u16* __restrict__ qr, const u16* __restrict__ kr,
    const u16* __restrict__ vsrc, const u16* __restrict__ lepeP,
    u16* __restrict__ outb)
{
    __shared__ u16 VT[4][64 * 72];   // V^T tile [d][k], pitch 72, swizzled
    __shared__ u16 PL[4][64 * 72];   // P tile [q][k], pitch 72; reused for O

    const int tid = threadIdx.x;
    const int w = tid >> 6, lane = tid & 63;
    const int l15 = lane & 15, l4 = lane >> 4;
    const int wid = blockIdx.x * 4 + w;
    const int b = wid >> 8, xy = (wid >> 2) & 63, n = wid & 3;

    size_t qkbase, vbase; int qkstride, vstride;
    if (AXIS == 0) {
        qkbase = ((size_t)(b * 4096 + xy * 64)) * 256 + n * 64;
        qkstride = 256;
        vbase = qkbase; vstride = 256;
    } else {
        qkbase = ((size_t)(b * 4096 + xy)) * 256 + n * 64;
        qkstride = 64 * 256;
        vbase = ((size_t)((b * 64 + xy) * 4 + n)) * 4096;
        vstride = 64;
    }

    u16* VTl = &VT[w][0];
    u16* PLl = &PL[w][0];

    // ---- V tile loads: rows k = it*8 + (lane>>3), 16B d-chunk (lane&7)
    bf16x8 vld[8];
    const int vrow = lane >> 3, vchunk = lane & 7;
#pragma unroll
    for (int it = 0; it < 8; ++it)
        vld[it] = *(const bf16x8*)(vsrc + vbase + (size_t)(it * 8 + vrow) * vstride + vchunk * 8);

    // ---- K (A-op) and Q (B-op) fragments straight from global
    bf16x8 ka[4][2], qb[4][2];
#pragma unroll
    for (int t = 0; t < 4; ++t)
#pragma unroll
        for (int ks = 0; ks < 2; ++ks) {
            ka[t][ks] = *(const bf16x8*)(kr + qkbase + (size_t)(t * 16 + l15) * qkstride + ks * 32 + l4 * 8);
            qb[t][ks] = *(const bf16x8*)(qr + qkbase + (size_t)(t * 16 + l15) * qkstride + ks * 32 + l4 * 8);
        }

    // ---- S^T = K·Q^T : lane holds S[q = qt*16+l15][k = kt*16 + l4*4 + rr]
    f32x4 sacc[4][4];   // [kt][qt]
#pragma unroll
    for (int kt = 0; kt < 4; ++kt)
#pragma unroll
        for (int qt = 0; qt < 4; ++qt) sacc[kt][qt] = (f32x4)0.f;
#pragma unroll
    for (int ks = 0; ks < 2; ++ks)
#pragma unroll
        for (int kt = 0; kt < 4; ++kt)
#pragma unroll
            for (int qt = 0; qt < 4; ++qt)
                sacc[kt][qt] = __builtin_amdgcn_mfma_f32_16x16x32_bf16(
                    ka[kt][ks], qb[qt][ks], sacc[kt][qt], 0, 0, 0);

    // ---- V^T transpose into LDS (granule-swizzled: g' = g ^ (d>>3))
#pragma unroll
    for (int it = 0; it < 8; ++it) {
        int gp = ((it ^ vchunk) << 3) + vrow;
#pragma unroll
        for (int j = 0; j < 8; ++j) {
            int d = vchunk * 8 + j;
            VTl[d * 72 + gp] = (u16)vld[it][j];
        }
    }

    // ---- softmax over k (mask |q-k|*decay folded; max-subtract skipped:
    //      |s| small, mask <= 0 -> exp in [2e-19, ~e])
    const float decay = logf(1.0f - exp2f(-(1.0f + 0.75f * (float)n)));
#pragma unroll
    for (int qt = 0; qt < 4; ++qt) {
        const int qq = qt * 16 + l15;
        float lsum = 0.f;
#pragma unroll
        for (int kt = 0; kt < 4; ++kt) {
            const int kb = kt * 16 + l4 * 4;
#pragma unroll
            for (int rr = 0; rr < 4; ++rr) {
                float s = sacc[kt][qt][rr] + fabsf((float)(qq - kb - rr)) * decay;
                s = __expf(s);
                sacc[kt][qt][rr] = s;
                lsum += s;
            }
        }
        lsum += __shfl_xor(lsum, 16);
        lsum += __shfl_xor(lsum, 32);
        const float rinv = 1.0f / lsum;
#pragma unroll
        for (int kt = 0; kt < 4; ++kt) {
            float e0 = sacc[kt][qt][0] * rinv, e1 = sacc[kt][qt][1] * rinv;
            float e2 = sacc[kt][qt][2] * rinv, e3 = sacc[kt][qt][3] * rinv;
            u32 p0, p1;
            asm("v_cvt_pk_bf16_f32 %0, %1, %2" : "=v"(p0) : "v"(e0), "v"(e1));
            asm("v_cvt_pk_bf16_f32 %0, %1, %2" : "=v"(p1) : "v"(e2), "v"(e3));
            uint2 pp; pp.x = p0; pp.y = p1;
            *(uint2*)(PLl + (qt * 16 + l15) * 72 + kt * 16 + l4 * 4) = pp;
        }
    }

    // ---- PV: O = P·V  (A = P rows from PL, B = V k-major from VT)
    __builtin_amdgcn_s_waitcnt(0xC07F);   // drain ds writes (cross-lane dep)
    bf16x8 pa[4][2], vb[4][2];
#pragma unroll
    for (int qt = 0; qt < 4; ++qt)
#pragma unroll
        for (int ks = 0; ks < 2; ++ks)
            pa[qt][ks] = *(const bf16x8*)(PLl + (qt * 16 + l15) * 72 + ks * 32 + l4 * 8);
#pragma unroll
    for (int dt = 0; dt < 4; ++dt)
#pragma unroll
        for (int ks = 0; ks < 2; ++ks) {
            int d = dt * 16 + l15;
            int g = (ks * 4 + l4) ^ (d >> 3);
            vb[dt][ks] = *(const bf16x8*)(VTl + d * 72 + g * 8);
        }

    f32x4 oacc[4][4];   // [qt][dt]
#pragma unroll
    for (int qt = 0; qt < 4; ++qt)
#pragma unroll
        for (int dt = 0; dt < 4; ++dt) oacc[qt][dt] = (f32x4)0.f;
#pragma unroll
    for (int ks = 0; ks < 2; ++ks)
#pragma unroll
        for (int qt = 0; qt < 4; ++qt)
#pragma unroll
            for (int dt = 0; dt < 4; ++dt)
                oacc[qt][dt] = __builtin_amdgcn_mfma_f32_16x16x32_bf16(
                    pa[qt][ks], vb[dt][ks], oacc[qt][dt], 0, 0, 0);

    // ---- restage O through LDS (reuse PL) so each lane stores one row
#pragma unroll
    for (int qt = 0; qt < 4; ++qt)
#pragma unroll
        for (int dt = 0; dt < 4; ++dt)
#pragma unroll
            for (int rr = 0; rr < 4; ++rr)
                PLl[(qt * 16 + l4 * 4 + rr) * 72 + dt * 16 + l15] = f2bf(oacc[qt][dt][rr]);
    __builtin_amdgcn_s_waitcnt(0xC07F);

    size_t orow;
    if (AXIS == 0) orow = ((size_t)((b * 64 + lane) * 4 + n)) * 4096 + xy * 64;
    else           orow = ((size_t)(b * 4096 + lane * 64 + xy)) * 256 + n * 64;
#pragma unroll
    for (int c = 0; c < 8; ++c) {
        bf16x8 o8 = *(const bf16x8*)(PLl + lane * 72 + c * 8);
        if (AXIS == 1) {
            bf16x8 lp = *(const bf16x8*)(lepeP + orow + c * 8);
            u16 hv[8];
#pragma unroll
            for (int j = 0; j < 8; ++j)
                hv[j] = f2bf(bf2f((u16)o8[j]) + bf2f((u16)lp[j]));
            o8 = *(bf16x8*)hv;
        }
        *(bf16x8*)(outb + orow + c * 8) = o8;
    }
}

// =============== 7. output projection (MFMA, transposed orient) =============
__global__ __launch_bounds__(256) void k_proj_mfma(
    const u16* __restrict__ WoT, const u16* __restrict__ attnL,
    const float* __restrict__ bo, float* __restrict__ y)
{
    __shared__ alignas(16) u16 Alds[128 * 64];
    __shared__ alignas(16) u16 Blds[128 * 64];

    const int t0 = blockIdx.x * 128;
    const int o0 = blockIdx.y * 128;
    const int tid = threadIdx.x;

    f32x4 acc[4][4];
#pragma unroll
    for (int mi = 0; mi < 4; mi++)
#pragma unroll
        for (int ni = 0; ni < 4; ni++) acc[mi][ni] = (f32x4)0.f;

    gemm_mainloop(WoT + (size_t)o0 * 256, attnL + (size_t)t0 * 256, Alds, Blds, tid, acc);

    const int lane = tid & 63, w = tid >> 6, wr = w >> 1, wc = w & 1;
    const int l15 = lane & 15, l4 = lane >> 4;
    const int b = t0 >> 12, sb = t0 & 4095;

#pragma unroll
    for (int mi = 0; mi < 4; mi++) {
#pragma unroll
        for (int rg = 0; rg < 4; rg++) {
            int o = o0 + wr * 64 + mi * 16 + l4 * 4 + rg;
            float bb = bo[o];
            float* yrow = y + ((size_t)(b * 256 + o)) * 4096 + sb + wc * 64;
#pragma unroll
            for (int ni = 0; ni < 4; ni++)
                yrow[ni * 16 + l15] = acc[mi][ni][rg] + bb;
        }
    }
}

// ============================ launcher ======================================
extern "C" void kernel_launch(void* const* d_in, const int* in_sizes, int n_in,
                              void* d_out, int out_size, void* d_ws, size_t ws_size,
                              hipStream_t stream)
{
    const float* x   = (const float*)d_in[0];
    const float* Wq  = (const float*)d_in[1];
    const float* bq  = (const float*)d_in[2];
    const float* Wk  = (const float*)d_in[3];
    const float* bk  = (const float*)d_in[4];
    const float* Wv  = (const float*)d_in[5];
    const float* bv  = (const float*)d_in[6];
    const float* dwk = (const float*)d_in[7];
    const float* dwb = (const float*)d_in[8];
    const float* Wo  = (const float*)d_in[9];
    const float* bo  = (const float*)d_in[10];
    float* y = (float*)d_out;

    char* ws = (char*)d_ws;
    const size_t MB = 1024 * 1024;
    float* sinT = (float*)(ws);                      // 512 KB
    float* cosT = (float*)(ws + 512 * 1024);         // 512 KB
    u16* WTq = (u16*)(ws + 1 * MB);                  // 4 x 128 KB
    u16* WTk = WTq + 65536;
    u16* WTv = WTk + 65536;
    u16* WoT = WTv + 65536;
    u16* qr   = (u16*)(ws + 2 * MB);                 // 32 MB each
    u16* kr   = (u16*)(ws + 2 * MB + 32 * MB);
    u16* v    = (u16*)(ws + 2 * MB + 64 * MB);
    u16* lepe = (u16*)(ws + 2 * MB + 96 * MB);
    u16* xT   = (u16*)(ws + 2 * MB + 128 * MB);      // dead after k_qkv_mfma
    u16* v5   = xT;                                   // reuse: (b,w,n,h,d)
    u16* attn = v;                                    // reuse (attn + lepe)

    k_tables<<<dim3(512), dim3(256), 0, stream>>>(sinT, cosT);
    k_prep_w<<<dim3(8, 8, 4), dim3(256), 0, stream>>>(Wq, Wk, Wv, Wo, WTq, WTk, WTv, WoT);
    k_prep_x<<<dim3(128, 8, 16), dim3(256), 0, stream>>>(x, xT);
    k_qkv_mfma<<<dim3(512, 2, 3), dim3(256), 0, stream>>>(
        xT, WTq, WTk, WTv, bq, bk, bv, sinT, cosT, qr, kr, v);
    k_lepe<<<dim3(64, 4, 16), dim3(256), 0, stream>>>(v, dwk, dwb, lepe);
    k_attn_mfma<0><<<dim3(1024), dim3(256), 0, stream>>>(qr, kr, v, nullptr, v5);
    k_attn_mfma<1><<<dim3(1024), dim3(256), 0, stream>>>(qr, kr, v5, lepe, attn);
    k_proj_mfma<<<dim3(512, 2), dim3(256), 0, stream>>>(WoT, attn, bo, y);
}

// Round 4
// 315.917 us; speedup vs baseline: 2.5700x; 1.0343x over previous
//
#include <hip/hip_runtime.h>
#include <hip/hip_bf16.h>

typedef unsigned short u16;
typedef unsigned int   u32;
typedef __attribute__((ext_vector_type(8))) short bf16x8;
typedef __attribute__((ext_vector_type(4))) float f32x4;

// ---------- bf16 helpers ----------
__device__ __forceinline__ float bf2f(u16 u) {
    union { u32 i; float f; } x; x.i = ((u32)u) << 16; return x.f;
}
__device__ __forceinline__ u16 f2bf(float f) {
    union { float f; u32 i; } x; x.f = f;
    u32 i = x.i;
    u32 r = (i + 0x7fffu + ((i >> 16) & 1u)) >> 16;  // RNE
    return (u16)r;
}

// =============== 1. sin/cos tables [4096][32] fp32 (pairs share angle) ======
__global__ void k_tables(float* __restrict__ sinT, float* __restrict__ cosT) {
    int id = blockIdx.x * 256 + threadIdx.x;   // 0..131071 = t*32+i
    int t = id >> 5, i = id & 31;
    double ang = pow(10000.0, -(double)i / 31.0);
    double a = (double)t * ang;
    sinT[id] = (float)sin(a);
    cosT[id] = (float)cos(a);
}

// =============== 2a. weight transpose+convert: WT[out][in] = W[in][out] =====
__global__ __launch_bounds__(256) void k_prep_w(
    const float* __restrict__ Wq, const float* __restrict__ Wk,
    const float* __restrict__ Wv, const float* __restrict__ Wo,
    u16* __restrict__ WTq, u16* __restrict__ WTk,
    u16* __restrict__ WTv, u16* __restrict__ WoT)
{
    __shared__ float T[32][33];
    int z = blockIdx.z;
    const float* W = (z == 0) ? Wq : (z == 1) ? Wk : (z == 2) ? Wv : Wo;
    u16* WT        = (z == 0) ? WTq : (z == 1) ? WTk : (z == 2) ? WTv : WoT;
    int n0 = blockIdx.x * 32, k0 = blockIdx.y * 32;
    int tx = threadIdx.x & 31, ty = threadIdx.x >> 5;   // ty 0..7
#pragma unroll
    for (int i = 0; i < 4; i++)
        T[ty * 4 + i][tx] = W[(k0 + ty * 4 + i) * 256 + n0 + tx];
    __syncthreads();
#pragma unroll
    for (int i = 0; i < 4; i++)
        WT[(n0 + ty * 4 + i) * 256 + k0 + tx] = f2bf(T[tx][ty * 4 + i]);
}

// =============== 2b. x transpose+convert: xT[b*4096+s][c] bf16 ==============
__global__ __launch_bounds__(256) void k_prep_x(
    const float* __restrict__ x, u16* __restrict__ xT)
{
    __shared__ float T[32][33];
    int b = blockIdx.z, c0 = blockIdx.y * 32, s0 = blockIdx.x * 32;
    int tx = threadIdx.x & 31, ty = threadIdx.x >> 5;
#pragma unroll
    for (int i = 0; i < 4; i++)
        T[ty * 4 + i][tx] = x[((size_t)(b * 256 + c0 + ty * 4 + i)) * 4096 + s0 + tx];
    __syncthreads();
#pragma unroll
    for (int i = 0; i < 4; i++)
        xT[((size_t)(b * 4096 + s0 + ty * 4 + i)) * 256 + c0 + tx] = f2bf(T[tx][ty * 4 + i]);
}

// =============== 3. fused QKV: A-tile resident, loop 3 mats =================
// grid 512 (token-tiles), block 512 (8 waves: wr=w>>2 over 2 token-halves,
// wc=w&3 over 4 outcol-quarters). A: 128x256 in LDS once. B: per-Kstep
// 256x64 slice, reg-prefetched depth 1. 12 K-steps per block.
__global__ __launch_bounds__(512, 2) void k_qkv_fused(
    const u16* __restrict__ xT, const u16* __restrict__ WTall,
    const float* __restrict__ bq, const float* __restrict__ bk,
    const float* __restrict__ bv,
    const float* __restrict__ sinT, const float* __restrict__ cosT,
    u16* __restrict__ qr, u16* __restrict__ kr, u16* __restrict__ vO)
{
    __shared__ alignas(16) u16 Alds[128 * 256];   // 64 KB
    __shared__ alignas(16) u16 Blds[256 * 64];    // 32 KB

    const int tid = threadIdx.x;
    const int t0 = blockIdx.x * 128;

    // staging coords
    const int ar = tid >> 5, ac = tid & 31;   // A: 16 rows/pass, 32 chunks/row
    const int br = tid >> 3, bc = tid & 7;    // B: 64 rows/pass, 8 chunks/row

    // ---- load whole A tile (8 x 16B/thread) + first B slice
    bf16x8 areg[8], breg[4];
#pragma unroll
    for (int p = 0; p < 8; ++p)
        areg[p] = *(const bf16x8*)(xT + (size_t)(t0 + p * 16 + ar) * 256 + ac * 8);
#pragma unroll
    for (int p = 0; p < 4; ++p)
        breg[p] = *(const bf16x8*)(WTall + (size_t)(p * 64 + br) * 256 + bc * 8);

    // ---- A -> LDS, chunk-swizzled (chunk' = c ^ (row&7))
#pragma unroll
    for (int p = 0; p < 8; ++p) {
        int r = p * 16 + ar;
        *(bf16x8*)(Alds + r * 256 + (ac ^ (r & 7)) * 8) = areg[p];
    }

    const int lane = tid & 63, w = tid >> 6;
    const int wr = w >> 2, wc = w & 3;
    const int l15 = lane & 15, l4 = lane >> 4, l7 = lane & 7;

#pragma unroll
    for (int mat = 0; mat < 3; ++mat) {
        f32x4 acc[4][4];
#pragma unroll
        for (int mi = 0; mi < 4; ++mi)
#pragma unroll
            for (int ni = 0; ni < 4; ++ni) acc[mi][ni] = (f32x4)0.f;

#pragma unroll
        for (int ks = 0; ks < 4; ++ks) {
            const int s = mat * 4 + ks;
            __syncthreads();                       // prior readers of Blds done
#pragma unroll
            for (int p = 0; p < 4; ++p) {
                int r = p * 64 + br;
                *(bf16x8*)(Blds + r * 64 + (bc ^ (r & 7)) * 8) = breg[p];
            }
            if (s < 11) {                          // prefetch next slice
                const int s2 = s + 1, mat2 = s2 >> 2, ks2 = s2 & 3;
#pragma unroll
                for (int p = 0; p < 4; ++p)
                    breg[p] = *(const bf16x8*)(WTall + (size_t)mat2 * 65536 +
                                (size_t)(p * 64 + br) * 256 + ks2 * 64 + bc * 8);
            }
            __syncthreads();
#pragma unroll
            for (int kk = 0; kk < 2; ++kk) {
                bf16x8 af[4], bfr[4];
#pragma unroll
                for (int mi = 0; mi < 4; ++mi) {
                    int r = wr * 64 + mi * 16 + l15;
                    af[mi] = *(const bf16x8*)(Alds + r * 256 + (ks * 8 + ((kk * 4 + l4) ^ l7)) * 8);
                }
#pragma unroll
                for (int ni = 0; ni < 4; ++ni) {
                    int r = wc * 64 + ni * 16 + l15;
                    bfr[ni] = *(const bf16x8*)(Blds + r * 64 + ((kk * 4 + l4) ^ l7) * 8);
                }
#pragma unroll
                for (int mi = 0; mi < 4; ++mi)
#pragma unroll
                    for (int ni = 0; ni < 4; ++ni)
                        acc[mi][ni] = __builtin_amdgcn_mfma_f32_16x16x32_bf16(
                            af[mi], bfr[ni], acc[mi][ni], 0, 0, 0);
            }
        }

        // ---- epilogue for this mat: bias (+ kscale + RoPE), paired bf16 store
        const float* bias = (mat == 0) ? bq : (mat == 1) ? bk : bv;
        u16* out          = (mat == 0) ? qr : (mat == 1) ? kr : vO;
        const float kscale = (mat == 1) ? 0.125f : 1.0f;
        float bcol[4]; int ip[4];
#pragma unroll
        for (int ni = 0; ni < 4; ++ni) {
            bcol[ni] = bias[wc * 64 + ni * 16 + l15];
            ip[ni] = ((ni * 16 + l15) & 63) >> 1;
        }
        const int srow0 = (t0 & 4095) + wr * 64;
#pragma unroll
        for (int mi = 0; mi < 4; ++mi) {
#pragma unroll
            for (int rg = 0; rg < 4; ++rg) {
                int s = srow0 + mi * 16 + l4 * 4 + rg;
                size_t trow = (size_t)(t0 + wr * 64 + mi * 16 + l4 * 4 + rg) * 256;
#pragma unroll
                for (int ni = 0; ni < 4; ++ni) {
                    float val = acc[mi][ni][rg] + bcol[ni];
                    float res;
                    if (mat != 2) {
                        val *= kscale;
                        float prt = __shfl_xor(val, 1);
                        float sv = sinT[s * 32 + ip[ni]];
                        float cv = cosT[s * 32 + ip[ni]];
                        res = (lane & 1) ? (val * cv + prt * sv) : (val * cv - prt * sv);
                    } else {
                        res = val;
                    }
                    float res2 = __shfl_xor(res, 1);
                    if (!(lane & 1)) {
                        int o = wc * 64 + ni * 16 + l15;
                        *(u32*)(out + trow + o) = (u32)f2bf(res) | ((u32)f2bf(res2) << 16);
                    }
                }
            }
        }
    }
}

// =============== 4. LEPE: 5x5 depthwise conv on v (NHWC) ====================
__global__ __launch_bounds__(256) void k_lepe(
    const u16* __restrict__ v, const float* __restrict__ dwk,
    const float* __restrict__ dwb, u16* __restrict__ lepe)
{
    __shared__ float Vh[12][12][64];
    __shared__ float Kl[25][64];
    const int b = blockIdx.z, cg = blockIdx.y * 64;
    const int ty0 = (blockIdx.x >> 3) * 8, tx0 = (blockIdx.x & 7) * 8;
    const int tid = threadIdx.x;

    for (int idx = tid; idx < 1600; idx += 256) {
        int tap = idx >> 6, c = idx & 63;
        Kl[tap][c] = dwk[tap * 256 + cg + c];
    }
#pragma unroll
    for (int qq = 0; qq < 36; ++qq) {
        int idx = qq * 256 + tid;
        int c = idx & 63, p = idx >> 6;
        int py = p / 12, px = p - py * 12;
        int gy = ty0 + py - 2, gx = tx0 + px - 2;
        float val = 0.f;
        if (gy >= 0 && gy < 64 && gx >= 0 && gx < 64)
            val = bf2f(v[(size_t)(b * 4096 + gy * 64 + gx) * 256 + cg + c]);
        Vh[py][px][c] = val;
    }
    __syncthreads();
    const int c = tid & 63, pg = tid >> 6;
    float kreg[25];
#pragma unroll
    for (int t = 0; t < 25; t++) kreg[t] = Kl[t][c];
    const float bias = dwb[cg + c];
#pragma unroll
    for (int pp = 0; pp < 16; ++pp) {
        int p = pg * 16 + pp;
        int oy = p >> 3, ox = p & 7;
        float a = bias;
#pragma unroll
        for (int dy = 0; dy < 5; ++dy)
#pragma unroll
            for (int dx = 0; dx < 5; ++dx)
                a += Vh[oy + dy][ox + dx][c] * kreg[dy * 5 + dx];
        lepe[(size_t)(b * 4096 + (ty0 + oy) * 64 + tx0 + ox) * 256 + cg + c] = f2bf(a);
    }
}

// =============== 5/6. Axial attention, per-wave MFMA flash ==================
template <int AXIS>
__global__ __launch_bounds__(256) void k_attn_mfma(
    const u16* __restrict__ qr, const u16* __restrict__ kr,
    const u16* __restrict__ vsrc, const u16* __restrict__ lepeP,
    u16* __restrict__ outb)
{
    __shared__ u16 VT[4][64 * 72];   // V^T tile [d][k], pitch 72, swizzled
    __shared__ u16 PL[4][64 * 72];   // P tile [q][k], pitch 72; reused for O

    const int tid = threadIdx.x;
    const int w = tid >> 6, lane = tid & 63;
    const int l15 = lane & 15, l4 = lane >> 4;
    const int wid = blockIdx.x * 4 + w;
    const int b = wid >> 8, xy = (wid >> 2) & 63, n = wid & 3;

    size_t qkbase, vbase; int qkstride, vstride;
    if (AXIS == 0) {
        qkbase = ((size_t)(b * 4096 + xy * 64)) * 256 + n * 64;
        qkstride = 256;
        vbase = qkbase; vstride = 256;
    } else {
        qkbase = ((size_t)(b * 4096 + xy)) * 256 + n * 64;
        qkstride = 64 * 256;
        vbase = ((size_t)((b * 64 + xy) * 4 + n)) * 4096;
        vstride = 64;
    }

    u16* VTl = &VT[w][0];
    u16* PLl = &PL[w][0];

    bf16x8 vld[8];
    const int vrow = lane >> 3, vchunk = lane & 7;
#pragma unroll
    for (int it = 0; it < 8; ++it)
        vld[it] = *(const bf16x8*)(vsrc + vbase + (size_t)(it * 8 + vrow) * vstride + vchunk * 8);

    bf16x8 ka[4][2], qb[4][2];
#pragma unroll
    for (int t = 0; t < 4; ++t)
#pragma unroll
        for (int ks = 0; ks < 2; ++ks) {
            ka[t][ks] = *(const bf16x8*)(kr + qkbase + (size_t)(t * 16 + l15) * qkstride + ks * 32 + l4 * 8);
            qb[t][ks] = *(const bf16x8*)(qr + qkbase + (size_t)(t * 16 + l15) * qkstride + ks * 32 + l4 * 8);
        }

    f32x4 sacc[4][4];   // [kt][qt]
#pragma unroll
    for (int kt = 0; kt < 4; ++kt)
#pragma unroll
        for (int qt = 0; qt < 4; ++qt) sacc[kt][qt] = (f32x4)0.f;
#pragma unroll
    for (int ks = 0; ks < 2; ++ks)
#pragma unroll
        for (int kt = 0; kt < 4; ++kt)
#pragma unroll
            for (int qt = 0; qt < 4; ++qt)
                sacc[kt][qt] = __builtin_amdgcn_mfma_f32_16x16x32_bf16(
                    ka[kt][ks], qb[qt][ks], sacc[kt][qt], 0, 0, 0);

#pragma unroll
    for (int it = 0; it < 8; ++it) {
        int gp = ((it ^ vchunk) << 3) + vrow;
#pragma unroll
        for (int j = 0; j < 8; ++j) {
            int d = vchunk * 8 + j;
            VTl[d * 72 + gp] = (u16)vld[it][j];
        }
    }

    const float decay = logf(1.0f - exp2f(-(1.0f + 0.75f * (float)n)));
#pragma unroll
    for (int qt = 0; qt < 4; ++qt) {
        const int qq = qt * 16 + l15;
        float lsum = 0.f;
#pragma unroll
        for (int kt = 0; kt < 4; ++kt) {
            const int kb = kt * 16 + l4 * 4;
#pragma unroll
            for (int rr = 0; rr < 4; ++rr) {
                float s = sacc[kt][qt][rr] + fabsf((float)(qq - kb - rr)) * decay;
                s = __expf(s);
                sacc[kt][qt][rr] = s;
                lsum += s;
            }
        }
        lsum += __shfl_xor(lsum, 16);
        lsum += __shfl_xor(lsum, 32);
        const float rinv = 1.0f / lsum;
#pragma unroll
        for (int kt = 0; kt < 4; ++kt) {
            float e0 = sacc[kt][qt][0] * rinv, e1 = sacc[kt][qt][1] * rinv;
            float e2 = sacc[kt][qt][2] * rinv, e3 = sacc[kt][qt][3] * rinv;
            u32 p0, p1;
            asm("v_cvt_pk_bf16_f32 %0, %1, %2" : "=v"(p0) : "v"(e0), "v"(e1));
            asm("v_cvt_pk_bf16_f32 %0, %1, %2" : "=v"(p1) : "v"(e2), "v"(e3));
            uint2 pp; pp.x = p0; pp.y = p1;
            *(uint2*)(PLl + (qt * 16 + l15) * 72 + kt * 16 + l4 * 4) = pp;
        }
    }

    __builtin_amdgcn_s_waitcnt(0xC07F);
    bf16x8 pa[4][2], vb[4][2];
#pragma unroll
    for (int qt = 0; qt < 4; ++qt)
#pragma unroll
        for (int ks = 0; ks < 2; ++ks)
            pa[qt][ks] = *(const bf16x8*)(PLl + (qt * 16 + l15) * 72 + ks * 32 + l4 * 8);
#pragma unroll
    for (int dt = 0; dt < 4; ++dt)
#pragma unroll
        for (int ks = 0; ks < 2; ++ks) {
            int d = dt * 16 + l15;
            int g = (ks * 4 + l4) ^ (d >> 3);
            vb[dt][ks] = *(const bf16x8*)(VTl + d * 72 + g * 8);
        }

    f32x4 oacc[4][4];   // [qt][dt]
#pragma unroll
    for (int qt = 0; qt < 4; ++qt)
#pragma unroll
        for (int dt = 0; dt < 4; ++dt) oacc[qt][dt] = (f32x4)0.f;
#pragma unroll
    for (int ks = 0; ks < 2; ++ks)
#pragma unroll
        for (int qt = 0; qt < 4; ++qt)
#pragma unroll
            for (int dt = 0; dt < 4; ++dt)
                oacc[qt][dt] = __builtin_amdgcn_mfma_f32_16x16x32_bf16(
                    pa[qt][ks], vb[dt][ks], oacc[qt][dt], 0, 0, 0);

#pragma unroll
    for (int qt = 0; qt < 4; ++qt)
#pragma unroll
        for (int dt = 0; dt < 4; ++dt)
#pragma unroll
            for (int rr = 0; rr < 4; ++rr)
                PLl[(qt * 16 + l4 * 4 + rr) * 72 + dt * 16 + l15] = f2bf(oacc[qt][dt][rr]);
    __builtin_amdgcn_s_waitcnt(0xC07F);

    size_t orow;
    if (AXIS == 0) orow = ((size_t)((b * 64 + lane) * 4 + n)) * 4096 + xy * 64;
    else           orow = ((size_t)(b * 4096 + lane * 64 + xy)) * 256 + n * 64;
#pragma unroll
    for (int c = 0; c < 8; ++c) {
        bf16x8 o8 = *(const bf16x8*)(PLl + lane * 72 + c * 8);
        if (AXIS == 1) {
            bf16x8 lp = *(const bf16x8*)(lepeP + orow + c * 8);
            u16 hv[8];
#pragma unroll
            for (int j = 0; j < 8; ++j)
                hv[j] = f2bf(bf2f((u16)o8[j]) + bf2f((u16)lp[j]));
            o8 = *(bf16x8*)hv;
        }
        *(bf16x8*)(outb + orow + c * 8) = o8;
    }
}

// =============== 7. fused output projection =================================
// D[o][t] = sum_k WoT[o][k]*attn[t][k]. Block: o-half(128) x 256 tokens.
// A = WoT-half resident in LDS; B = attn 256x64 K-slices, depth-1 prefetch.
// Chunked XCD swizzle pairs the two o-halves of a token tile on one XCD.
__global__ __launch_bounds__(512, 2) void k_proj_fused(
    const u16* __restrict__ WoT, const u16* __restrict__ attnL,
    const float* __restrict__ bo, float* __restrict__ y)
{
    __shared__ alignas(16) u16 Alds[128 * 256];   // 64 KB
    __shared__ alignas(16) u16 Blds[256 * 64];    // 32 KB

    const int tid = threadIdx.x;
    const int bid = blockIdx.x;                   // 512 blocks
    const int xcd = bid & 7, slot = bid >> 3;     // slot 0..63
    const int tt = xcd * 32 + (slot >> 1);        // token tile 0..255
    const int oh = slot & 1;
    const int t0 = tt * 256;
    const int o0 = oh * 128;

    const int ar = tid >> 5, ac = tid & 31;
    const int br = tid >> 3, bc = tid & 7;

    bf16x8 areg[8], breg[4];
#pragma unroll
    for (int p = 0; p < 8; ++p)
        areg[p] = *(const bf16x8*)(WoT + (size_t)(o0 + p * 16 + ar) * 256 + ac * 8);
#pragma unroll
    for (int p = 0; p < 4; ++p)
        breg[p] = *(const bf16x8*)(attnL + (size_t)(t0 + p * 64 + br) * 256 + bc * 8);

#pragma unroll
    for (int p = 0; p < 8; ++p) {
        int r = p * 16 + ar;
        *(bf16x8*)(Alds + r * 256 + (ac ^ (r & 7)) * 8) = areg[p];
    }

    const int lane = tid & 63, w = tid >> 6;
    const int wr = w >> 2, wc = w & 3;
    const int l15 = lane & 15, l4 = lane >> 4, l7 = lane & 7;

    f32x4 acc[4][4];
#pragma unroll
    for (int mi = 0; mi < 4; ++mi)
#pragma unroll
        for (int ni = 0; ni < 4; ++ni) acc[mi][ni] = (f32x4)0.f;

#pragma unroll
    for (int ks = 0; ks < 4; ++ks) {
        __syncthreads();
#pragma unroll
        for (int p = 0; p < 4; ++p) {
            int r = p * 64 + br;
            *(bf16x8*)(Blds + r * 64 + (bc ^ (r & 7)) * 8) = breg[p];
        }
        if (ks < 3) {
#pragma unroll
            for (int p = 0; p < 4; ++p)
                breg[p] = *(const bf16x8*)(attnL + (size_t)(t0 + p * 64 + br) * 256 + (ks + 1) * 64 + bc * 8);
        }
        __syncthreads();
#pragma unroll
        for (int kk = 0; kk < 2; ++kk) {
            bf16x8 af[4], bfr[4];
#pragma unroll
            for (int mi = 0; mi < 4; ++mi) {
                int r = wr * 64 + mi * 16 + l15;
                af[mi] = *(const bf16x8*)(Alds + r * 256 + (ks * 8 + ((kk * 4 + l4) ^ l7)) * 8);
            }
#pragma unroll
            for (int ni = 0; ni < 4; ++ni) {
                int r = wc * 64 + ni * 16 + l15;
                bfr[ni] = *(const bf16x8*)(Blds + r * 64 + ((kk * 4 + l4) ^ l7) * 8);
            }
#pragma unroll
            for (int mi = 0; mi < 4; ++mi)
#pragma unroll
                for (int ni = 0; ni < 4; ++ni)
                    acc[mi][ni] = __builtin_amdgcn_mfma_f32_16x16x32_bf16(
                        af[mi], bfr[ni], acc[mi][ni], 0, 0, 0);
        }
    }

    const int b = t0 >> 12, sb = t0 & 4095;
#pragma unroll
    for (int mi = 0; mi < 4; ++mi) {
#pragma unroll
        for (int rg = 0; rg < 4; ++rg) {
            int o = o0 + wr * 64 + mi * 16 + l4 * 4 + rg;
            float bb = bo[o];
            float* yrow = y + ((size_t)(b * 256 + o)) * 4096 + sb + wc * 64;
#pragma unroll
            for (int ni = 0; ni < 4; ++ni)
                yrow[ni * 16 + l15] = acc[mi][ni][rg] + bb;
        }
    }
}

// ============================ launcher ======================================
extern "C" void kernel_launch(void* const* d_in, const int* in_sizes, int n_in,
                              void* d_out, int out_size, void* d_ws, size_t ws_size,
                              hipStream_t stream)
{
    const float* x   = (const float*)d_in[0];
    const float* Wq  = (const float*)d_in[1];
    const float* bq  = (const float*)d_in[2];
    const float* Wk  = (const float*)d_in[3];
    const float* bk  = (const float*)d_in[4];
    const float* Wv  = (const float*)d_in[5];
    const float* bv  = (const float*)d_in[6];
    const float* dwk = (const float*)d_in[7];
    const float* dwb = (const float*)d_in[8];
    const float* Wo  = (const float*)d_in[9];
    const float* bo  = (const float*)d_in[10];
    float* y = (float*)d_out;

    char* ws = (char*)d_ws;
    const size_t MB = 1024 * 1024;
    float* sinT = (float*)(ws);                      // 512 KB
    float* cosT = (float*)(ws + 512 * 1024);         // 512 KB
    u16* WTq = (u16*)(ws + 1 * MB);                  // 4 x 128 KB (contiguous)
    u16* WTk = WTq + 65536;
    u16* WTv = WTk + 65536;
    u16* WoT = WTv + 65536;
    u16* qr   = (u16*)(ws + 2 * MB);                 // 32 MB each
    u16* kr   = (u16*)(ws + 2 * MB + 32 * MB);
    u16* v    = (u16*)(ws + 2 * MB + 64 * MB);
    u16* lepe = (u16*)(ws + 2 * MB + 96 * MB);
    u16* xT   = (u16*)(ws + 2 * MB + 128 * MB);      // dead after k_qkv_fused
    u16* v5   = xT;                                   // reuse: (b,w,n,h,d)
    u16* attn = v;                                    // reuse (attn + lepe)

    k_tables<<<dim3(512), dim3(256), 0, stream>>>(sinT, cosT);
    k_prep_w<<<dim3(8, 8, 4), dim3(256), 0, stream>>>(Wq, Wk, Wv, Wo, WTq, WTk, WTv, WoT);
    k_prep_x<<<dim3(128, 8, 16), dim3(256), 0, stream>>>(x, xT);
    k_qkv_fused<<<dim3(512), dim3(512), 0, stream>>>(
        xT, WTq, bq, bk, bv, sinT, cosT, qr, kr, v);
    k_lepe<<<dim3(64, 4, 16), dim3(256), 0, stream>>>(v, dwk, dwb, lepe);
    k_attn_mfma<0><<<dim3(1024), dim3(256), 0, stream>>>(qr, kr, v, nullptr, v5);
    k_attn_mfma<1><<<dim3(1024), dim3(256), 0, stream>>>(qr, kr, v5, lepe, attn);
    k_proj_fused<<<dim3(512), dim3(512), 0, stream>>>(WoT, attn, bo, y);
}

// Round 5
// 272.534 us; speedup vs baseline: 2.9792x; 1.1592x over previous
//
#include <hip/hip_runtime.h>
#include <hip/hip_bf16.h>

typedef unsigned short u16;
typedef unsigned int   u32;
typedef __attribute__((ext_vector_type(8))) short bf16x8;
typedef __attribute__((ext_vector_type(4))) float f32x4;

// ---------- bf16 helpers ----------
__device__ __forceinline__ float bf2f(u16 u) {
    union { u32 i; float f; } x; x.i = ((u32)u) << 16; return x.f;
}
__device__ __forceinline__ u16 f2bf(float f) {
    union { float f; u32 i; } x; x.f = f;
    u32 i = x.i;
    u32 r = (i + 0x7fffu + ((i >> 16) & 1u)) >> 16;  // RNE
    return (u16)r;
}

// =============== 1. sin/cos tables [4096][32] fp32 (pairs share angle) ======
__global__ void k_tables(float* __restrict__ sinT, float* __restrict__ cosT) {
    int id = blockIdx.x * 256 + threadIdx.x;   // 0..131071 = t*32+i
    int t = id >> 5, i = id & 31;
    double ang = pow(10000.0, -(double)i / 31.0);
    double a = (double)t * ang;
    sinT[id] = (float)sin(a);
    cosT[id] = (float)cos(a);
}

// =============== 2a. weight transpose+convert: WT[out][in] = W[in][out] =====
__global__ __launch_bounds__(256) void k_prep_w(
    const float* __restrict__ Wq, const float* __restrict__ Wk,
    const float* __restrict__ Wv, const float* __restrict__ Wo,
    u16* __restrict__ WTq, u16* __restrict__ WTk,
    u16* __restrict__ WTv, u16* __restrict__ WoT)
{
    __shared__ float T[32][33];
    int z = blockIdx.z;
    const float* W = (z == 0) ? Wq : (z == 1) ? Wk : (z == 2) ? Wv : Wo;
    u16* WT        = (z == 0) ? WTq : (z == 1) ? WTk : (z == 2) ? WTv : WoT;
    int n0 = blockIdx.x * 32, k0 = blockIdx.y * 32;
    int tx = threadIdx.x & 31, ty = threadIdx.x >> 5;   // ty 0..7
#pragma unroll
    for (int i = 0; i < 4; i++)
        T[ty * 4 + i][tx] = W[(k0 + ty * 4 + i) * 256 + n0 + tx];
    __syncthreads();
#pragma unroll
    for (int i = 0; i < 4; i++)
        WT[(n0 + ty * 4 + i) * 256 + k0 + tx] = f2bf(T[tx][ty * 4 + i]);
}

// =============== 2b. x transpose+convert: xT[b*4096+s][c] bf16 ==============
__global__ __launch_bounds__(256) void k_prep_x(
    const float* __restrict__ x, u16* __restrict__ xT)
{
    __shared__ float T[32][33];
    int b = blockIdx.z, c0 = blockIdx.y * 32, s0 = blockIdx.x * 32;
    int tx = threadIdx.x & 31, ty = threadIdx.x >> 5;
#pragma unroll
    for (int i = 0; i < 4; i++)
        T[ty * 4 + i][tx] = x[((size_t)(b * 256 + c0 + ty * 4 + i)) * 4096 + s0 + tx];
    __syncthreads();
#pragma unroll
    for (int i = 0; i < 4; i++)
        xT[((size_t)(b * 4096 + s0 + ty * 4 + i)) * 256 + c0 + tx] = f2bf(T[tx][ty * 4 + i]);
}

// =============== 3. fused QKV: A-tile resident, loop 3 mats =================
// grid 512 (token-tiles), block 512 (8 waves). A: 128x256 in LDS once.
// B: per-Kstep 256x64 slice; loads for step s+1 issued at the TOP of
// compute(s) so the vmcnt(0) drain at the next barrier lands after a full
// MFMA phase (2-phase pipeline, T3 ordering). RoPE sin/cos staged in LDS.
__global__ __launch_bounds__(512, 1) void k_qkv_fused(
    const u16* __restrict__ xT, const u16* __restrict__ WTall,
    const float* __restrict__ bq, const float* __restrict__ bk,
    const float* __restrict__ bv,
    const float* __restrict__ sinT, const float* __restrict__ cosT,
    u16* __restrict__ qr, u16* __restrict__ kr, u16* __restrict__ vO)
{
    __shared__ alignas(16) u16 Alds[128 * 256];   // 64 KB
    __shared__ alignas(16) u16 Blds[256 * 64];    // 32 KB
    __shared__ float2 SL[128 * 32];               // 32 KB (cos, sin)

    const int tid = threadIdx.x;
    const int t0 = blockIdx.x * 128;

    const int ar = tid >> 5, ac = tid & 31;   // A staging
    const int br = tid >> 3, bc = tid & 7;    // B staging

    // ---- load whole A tile + first B slice
    bf16x8 areg[8], breg[4];
#pragma unroll
    for (int p = 0; p < 8; ++p)
        areg[p] = *(const bf16x8*)(xT + (size_t)(t0 + p * 16 + ar) * 256 + ac * 8);
#pragma unroll
    for (int p = 0; p < 4; ++p)
        breg[p] = *(const bf16x8*)(WTall + (size_t)(p * 64 + br) * 256 + bc * 8);

    // ---- A -> LDS, chunk-swizzled
#pragma unroll
    for (int p = 0; p < 8; ++p) {
        int r = p * 16 + ar;
        *(bf16x8*)(Alds + r * 256 + (ac ^ (r & 7)) * 8) = areg[p];
    }
    // ---- stage RoPE cos/sin slice for this block's 128 tokens
    {
        const int sb = t0 & 4095;
#pragma unroll
        for (int p = 0; p < 8; ++p) {
            int idx = p * 512 + tid;            // 0..4095 = sl*32 + ii
            int sl = idx >> 5, ii = idx & 31;
            SL[idx] = make_float2(cosT[(sb + sl) * 32 + ii], sinT[(sb + sl) * 32 + ii]);
        }
    }

    const int lane = tid & 63, w = tid >> 6;
    const int wr = w >> 2, wc = w & 3;
    const int l15 = lane & 15, l4 = lane >> 4, l7 = lane & 7;

#pragma unroll
    for (int mat = 0; mat < 3; ++mat) {
        f32x4 acc[4][4];
#pragma unroll
        for (int mi = 0; mi < 4; ++mi)
#pragma unroll
            for (int ni = 0; ni < 4; ++ni) acc[mi][ni] = (f32x4)0.f;

#pragma unroll
        for (int ks = 0; ks < 4; ++ks) {
            const int s = mat * 4 + ks;
            __syncthreads();                       // readers of prev Blds done
#pragma unroll
            for (int p = 0; p < 4; ++p) {
                int r = p * 64 + br;
                *(bf16x8*)(Blds + r * 64 + (bc ^ (r & 7)) * 8) = breg[p];
            }
            __syncthreads();                       // Blds ready
            if (s < 11) {                          // issue next loads NOW —
                const int s2 = s + 1;              // hidden under the MFMAs
                const int mat2 = s2 >> 2, ks2 = s2 & 3;
#pragma unroll
                for (int p = 0; p < 4; ++p)
                    breg[p] = *(const bf16x8*)(WTall + (size_t)mat2 * 65536 +
                                (size_t)(p * 64 + br) * 256 + ks2 * 64 + bc * 8);
            }
#pragma unroll
            for (int kk = 0; kk < 2; ++kk) {
                bf16x8 af[4], bfr[4];
#pragma unroll
                for (int mi = 0; mi < 4; ++mi) {
                    int r = wr * 64 + mi * 16 + l15;
                    af[mi] = *(const bf16x8*)(Alds + r * 256 + (ks * 8 + ((kk * 4 + l4) ^ l7)) * 8);
                }
#pragma unroll
                for (int ni = 0; ni < 4; ++ni) {
                    int r = wc * 64 + ni * 16 + l15;
                    bfr[ni] = *(const bf16x8*)(Blds + r * 64 + ((kk * 4 + l4) ^ l7) * 8);
                }
#pragma unroll
                for (int mi = 0; mi < 4; ++mi)
#pragma unroll
                    for (int ni = 0; ni < 4; ++ni)
                        acc[mi][ni] = __builtin_amdgcn_mfma_f32_16x16x32_bf16(
                            af[mi], bfr[ni], acc[mi][ni], 0, 0, 0);
            }
        }

        // ---- epilogue: bias (+ kscale + RoPE from LDS), cvt_pk paired store
        const float* bias = (mat == 0) ? bq : (mat == 1) ? bk : bv;
        u16* out          = (mat == 0) ? qr : (mat == 1) ? kr : vO;
        const float kscale = (mat == 1) ? 0.125f : 1.0f;
        float bcol[4]; int ip[4];
#pragma unroll
        for (int ni = 0; ni < 4; ++ni) {
            bcol[ni] = bias[wc * 64 + ni * 16 + l15];
            ip[ni] = (ni * 16 + l15) >> 1;
        }
#pragma unroll
        for (int mi = 0; mi < 4; ++mi) {
#pragma unroll
            for (int rg = 0; rg < 4; ++rg) {
                const int sl = wr * 64 + mi * 16 + l4 * 4 + rg;   // local token
                size_t trow = (size_t)(t0 + sl) * 256;
#pragma unroll
                for (int ni = 0; ni < 4; ++ni) {
                    float val = acc[mi][ni][rg] + bcol[ni];
                    float res;
                    if (mat != 2) {
                        val *= kscale;
                        float prt = __shfl_xor(val, 1);
                        float2 cs = SL[sl * 32 + ip[ni]];
                        res = (lane & 1) ? fmaf(val, cs.x,  prt * cs.y)
                                         : fmaf(val, cs.x, -prt * cs.y);
                    } else {
                        res = val;
                    }
                    float res2 = __shfl_xor(res, 1);
                    if (!(lane & 1)) {
                        u32 pk;
                        asm("v_cvt_pk_bf16_f32 %0, %1, %2" : "=v"(pk) : "v"(res), "v"(res2));
                        int o = wc * 64 + ni * 16 + l15;
                        *(u32*)(out + trow + o) = pk;
                    }
                }
            }
        }
    }
}

// =============== 4. LEPE: 5x5 depthwise conv on v (NHWC) ====================
__global__ __launch_bounds__(256) void k_lepe(
    const u16* __restrict__ v, const float* __restrict__ dwk,
    const float* __restrict__ dwb, u16* __restrict__ lepe)
{
    __shared__ float Vh[12][12][64];
    __shared__ float Kl[25][64];
    const int b = blockIdx.z, cg = blockIdx.y * 64;
    const int ty0 = (blockIdx.x >> 3) * 8, tx0 = (blockIdx.x & 7) * 8;
    const int tid = threadIdx.x;

    for (int idx = tid; idx < 1600; idx += 256) {
        int tap = idx >> 6, c = idx & 63;
        Kl[tap][c] = dwk[tap * 256 + cg + c];
    }
#pragma unroll
    for (int qq = 0; qq < 36; ++qq) {
        int idx = qq * 256 + tid;
        int c = idx & 63, p = idx >> 6;
        int py = p / 12, px = p - py * 12;
        int gy = ty0 + py - 2, gx = tx0 + px - 2;
        float val = 0.f;
        if (gy >= 0 && gy < 64 && gx >= 0 && gx < 64)
            val = bf2f(v[(size_t)(b * 4096 + gy * 64 + gx) * 256 + cg + c]);
        Vh[py][px][c] = val;
    }
    __syncthreads();
    const int c = tid & 63, pg = tid >> 6;
    float kreg[25];
#pragma unroll
    for (int t = 0; t < 25; t++) kreg[t] = Kl[t][c];
    const float bias = dwb[cg + c];
#pragma unroll
    for (int pp = 0; pp < 16; ++pp) {
        int p = pg * 16 + pp;
        int oy = p >> 3, ox = p & 7;
        float a = bias;
#pragma unroll
        for (int dy = 0; dy < 5; ++dy)
#pragma unroll
            for (int dx = 0; dx < 5; ++dx)
                a += Vh[oy + dy][ox + dx][c] * kreg[dy * 5 + dx];
        lepe[(size_t)(b * 4096 + (ty0 + oy) * 64 + tx0 + ox) * 256 + cg + c] = f2bf(a);
    }
}

// =============== 5/6. Axial attention, per-wave MFMA flash ==================
template <int AXIS>
__global__ __launch_bounds__(256) void k_attn_mfma(
    const u16* __restrict__ qr, const u16* __restrict__ kr,
    const u16* __restrict__ vsrc, const u16* __restrict__ lepeP,
    u16* __restrict__ outb)
{
    __shared__ u16 VT[4][64 * 72];   // V^T tile [d][k], pitch 72, swizzled
    __shared__ u16 PL[4][64 * 72];   // P tile [q][k], pitch 72; reused for O

    const int tid = threadIdx.x;
    const int w = tid >> 6, lane = tid & 63;
    const int l15 = lane & 15, l4 = lane >> 4;
    const int wid = blockIdx.x * 4 + w;
    const int b = wid >> 8, xy = (wid >> 2) & 63, n = wid & 3;

    size_t qkbase, vbase; int qkstride, vstride;
    if (AXIS == 0) {
        qkbase = ((size_t)(b * 4096 + xy * 64)) * 256 + n * 64;
        qkstride = 256;
        vbase = qkbase; vstride = 256;
    } else {
        qkbase = ((size_t)(b * 4096 + xy)) * 256 + n * 64;
        qkstride = 64 * 256;
        vbase = ((size_t)((b * 64 + xy) * 4 + n)) * 4096;
        vstride = 64;
    }

    u16* VTl = &VT[w][0];
    u16* PLl = &PL[w][0];

    bf16x8 vld[8];
    const int vrow = lane >> 3, vchunk = lane & 7;
#pragma unroll
    for (int it = 0; it < 8; ++it)
        vld[it] = *(const bf16x8*)(vsrc + vbase + (size_t)(it * 8 + vrow) * vstride + vchunk * 8);

    bf16x8 ka[4][2], qb[4][2];
#pragma unroll
    for (int t = 0; t < 4; ++t)
#pragma unroll
        for (int ks = 0; ks < 2; ++ks) {
            ka[t][ks] = *(const bf16x8*)(kr + qkbase + (size_t)(t * 16 + l15) * qkstride + ks * 32 + l4 * 8);
            qb[t][ks] = *(const bf16x8*)(qr + qkbase + (size_t)(t * 16 + l15) * qkstride + ks * 32 + l4 * 8);
        }

    f32x4 sacc[4][4];   // [kt][qt]
#pragma unroll
    for (int kt = 0; kt < 4; ++kt)
#pragma unroll
        for (int qt = 0; qt < 4; ++qt) sacc[kt][qt] = (f32x4)0.f;
#pragma unroll
    for (int ks = 0; ks < 2; ++ks)
#pragma unroll
        for (int kt = 0; kt < 4; ++kt)
#pragma unroll
            for (int qt = 0; qt < 4; ++qt)
                sacc[kt][qt] = __builtin_amdgcn_mfma_f32_16x16x32_bf16(
                    ka[kt][ks], qb[qt][ks], sacc[kt][qt], 0, 0, 0);

#pragma unroll
    for (int it = 0; it < 8; ++it) {
        int gp = ((it ^ vchunk) << 3) + vrow;
#pragma unroll
        for (int j = 0; j < 8; ++j) {
            int d = vchunk * 8 + j;
            VTl[d * 72 + gp] = (u16)vld[it][j];
        }
    }

    const float decay = logf(1.0f - exp2f(-(1.0f + 0.75f * (float)n)));
#pragma unroll
    for (int qt = 0; qt < 4; ++qt) {
        const int qq = qt * 16 + l15;
        float lsum = 0.f;
#pragma unroll
        for (int kt = 0; kt < 4; ++kt) {
            const int kb = kt * 16 + l4 * 4;
#pragma unroll
            for (int rr = 0; rr < 4; ++rr) {
                float s = sacc[kt][qt][rr] + fabsf((float)(qq - kb - rr)) * decay;
                s = __expf(s);
                sacc[kt][qt][rr] = s;
                lsum += s;
            }
        }
        lsum += __shfl_xor(lsum, 16);
        lsum += __shfl_xor(lsum, 32);
        const float rinv = 1.0f / lsum;
#pragma unroll
        for (int kt = 0; kt < 4; ++kt) {
            float e0 = sacc[kt][qt][0] * rinv, e1 = sacc[kt][qt][1] * rinv;
            float e2 = sacc[kt][qt][2] * rinv, e3 = sacc[kt][qt][3] * rinv;
            u32 p0, p1;
            asm("v_cvt_pk_bf16_f32 %0, %1, %2" : "=v"(p0) : "v"(e0), "v"(e1));
            asm("v_cvt_pk_bf16_f32 %0, %1, %2" : "=v"(p1) : "v"(e2), "v"(e3));
            uint2 pp; pp.x = p0; pp.y = p1;
            *(uint2*)(PLl + (qt * 16 + l15) * 72 + kt * 16 + l4 * 4) = pp;
        }
    }

    __builtin_amdgcn_s_waitcnt(0xC07F);
    bf16x8 pa[4][2], vb[4][2];
#pragma unroll
    for (int qt = 0; qt < 4; ++qt)
#pragma unroll
        for (int ks = 0; ks < 2; ++ks)
            pa[qt][ks] = *(const bf16x8*)(PLl + (qt * 16 + l15) * 72 + ks * 32 + l4 * 8);
#pragma unroll
    for (int dt = 0; dt < 4; ++dt)
#pragma unroll
        for (int ks = 0; ks < 2; ++ks) {
            int d = dt * 16 + l15;
            int g = (ks * 4 + l4) ^ (d >> 3);
            vb[dt][ks] = *(const bf16x8*)(VTl + d * 72 + g * 8);
        }

    f32x4 oacc[4][4];   // [qt][dt]
#pragma unroll
    for (int qt = 0; qt < 4; ++qt)
#pragma unroll
        for (int dt = 0; dt < 4; ++dt) oacc[qt][dt] = (f32x4)0.f;
#pragma unroll
    for (int ks = 0; ks < 2; ++ks)
#pragma unroll
        for (int qt = 0; qt < 4; ++qt)
#pragma unroll
            for (int dt = 0; dt < 4; ++dt)
                oacc[qt][dt] = __builtin_amdgcn_mfma_f32_16x16x32_bf16(
                    pa[qt][ks], vb[dt][ks], oacc[qt][dt], 0, 0, 0);

#pragma unroll
    for (int qt = 0; qt < 4; ++qt)
#pragma unroll
        for (int dt = 0; dt < 4; ++dt)
#pragma unroll
            for (int rr = 0; rr < 4; ++rr)
                PLl[(qt * 16 + l4 * 4 + rr) * 72 + dt * 16 + l15] = f2bf(oacc[qt][dt][rr]);
    __builtin_amdgcn_s_waitcnt(0xC07F);

    size_t orow;
    if (AXIS == 0) orow = ((size_t)((b * 64 + lane) * 4 + n)) * 4096 + xy * 64;
    else           orow = ((size_t)(b * 4096 + lane * 64 + xy)) * 256 + n * 64;
#pragma unroll
    for (int c = 0; c < 8; ++c) {
        bf16x8 o8 = *(const bf16x8*)(PLl + lane * 72 + c * 8);
        if (AXIS == 1) {
            bf16x8 lp = *(const bf16x8*)(lepeP + orow + c * 8);
            u16 hv[8];
#pragma unroll
            for (int j = 0; j < 8; ++j)
                hv[j] = f2bf(bf2f((u16)o8[j]) + bf2f((u16)lp[j]));
            o8 = *(bf16x8*)hv;
        }
        *(bf16x8*)(outb + orow + c * 8) = o8;
    }
}

// =============== 7. fused output projection =================================
__global__ __launch_bounds__(512, 1) void k_proj_fused(
    const u16* __restrict__ WoT, const u16* __restrict__ attnL,
    const float* __restrict__ bo, float* __restrict__ y)
{
    __shared__ alignas(16) u16 Alds[128 * 256];   // 64 KB
    __shared__ alignas(16) u16 Blds[256 * 64];    // 32 KB

    const int tid = threadIdx.x;
    const int bid = blockIdx.x;                   // 512 blocks
    const int xcd = bid & 7, slot = bid >> 3;
    const int tt = xcd * 32 + (slot >> 1);
    const int oh = slot & 1;
    const int t0 = tt * 256;
    const int o0 = oh * 128;

    const int ar = tid >> 5, ac = tid & 31;
    const int br = tid >> 3, bc = tid & 7;

    bf16x8 areg[8], breg[4];
#pragma unroll
    for (int p = 0; p < 8; ++p)
        areg[p] = *(const bf16x8*)(WoT + (size_t)(o0 + p * 16 + ar) * 256 + ac * 8);
#pragma unroll
    for (int p = 0; p < 4; ++p)
        breg[p] = *(const bf16x8*)(attnL + (size_t)(t0 + p * 64 + br) * 256 + bc * 8);

#pragma unroll
    for (int p = 0; p < 8; ++p) {
        int r = p * 16 + ar;
        *(bf16x8*)(Alds + r * 256 + (ac ^ (r & 7)) * 8) = areg[p];
    }

    const int lane = tid & 63, w = tid >> 6;
    const int wr = w >> 2, wc = w & 3;
    const int l15 = lane & 15, l4 = lane >> 4, l7 = lane & 7;

    f32x4 acc[4][4];
#pragma unroll
    for (int mi = 0; mi < 4; ++mi)
#pragma unroll
        for (int ni = 0; ni < 4; ++ni) acc[mi][ni] = (f32x4)0.f;

#pragma unroll
    for (int ks = 0; ks < 4; ++ks) {
        __syncthreads();
#pragma unroll
        for (int p = 0; p < 4; ++p) {
            int r = p * 64 + br;
            *(bf16x8*)(Blds + r * 64 + (bc ^ (r & 7)) * 8) = breg[p];
        }
        __syncthreads();
        if (ks < 3) {                              // issue next loads under MFMA
#pragma unroll
            for (int p = 0; p < 4; ++p)
                breg[p] = *(const bf16x8*)(attnL + (size_t)(t0 + p * 64 + br) * 256 + (ks + 1) * 64 + bc * 8);
        }
#pragma unroll
        for (int kk = 0; kk < 2; ++kk) {
            bf16x8 af[4], bfr[4];
#pragma unroll
            for (int mi = 0; mi < 4; ++mi) {
                int r = wr * 64 + mi * 16 + l15;
                af[mi] = *(const bf16x8*)(Alds + r * 256 + (ks * 8 + ((kk * 4 + l4) ^ l7)) * 8);
            }
#pragma unroll
            for (int ni = 0; ni < 4; ++ni) {
                int r = wc * 64 + ni * 16 + l15;
                bfr[ni] = *(const bf16x8*)(Blds + r * 64 + ((kk * 4 + l4) ^ l7) * 8);
            }
#pragma unroll
            for (int mi = 0; mi < 4; ++mi)
#pragma unroll
                for (int ni = 0; ni < 4; ++ni)
                    acc[mi][ni] = __builtin_amdgcn_mfma_f32_16x16x32_bf16(
                        af[mi], bfr[ni], acc[mi][ni], 0, 0, 0);
        }
    }

    const int b = t0 >> 12, sb = t0 & 4095;
#pragma unroll
    for (int mi = 0; mi < 4; ++mi) {
#pragma unroll
        for (int rg = 0; rg < 4; ++rg) {
            int o = o0 + wr * 64 + mi * 16 + l4 * 4 + rg;
            float bb = bo[o];
            float* yrow = y + ((size_t)(b * 256 + o)) * 4096 + sb + wc * 64;
#pragma unroll
            for (int ni = 0; ni < 4; ++ni)
                yrow[ni * 16 + l15] = acc[mi][ni][rg] + bb;
        }
    }
}

// ============================ launcher ======================================
extern "C" void kernel_launch(void* const* d_in, const int* in_sizes, int n_in,
                              void* d_out, int out_size, void* d_ws, size_t ws_size,
                              hipStream_t stream)
{
    const float* x   = (const float*)d_in[0];
    const float* Wq  = (const float*)d_in[1];
    const float* bq  = (const float*)d_in[2];
    const float* Wk  = (const float*)d_in[3];
    const float* bk  = (const float*)d_in[4];
    const float* Wv  = (const float*)d_in[5];
    const float* bv  = (const float*)d_in[6];
    const float* dwk = (const float*)d_in[7];
    const float* dwb = (const float*)d_in[8];
    const float* Wo  = (const float*)d_in[9];
    const float* bo  = (const float*)d_in[10];
    float* y = (float*)d_out;

    char* ws = (char*)d_ws;
    const size_t MB = 1024 * 1024;
    float* sinT = (float*)(ws);                      // 512 KB
    float* cosT = (float*)(ws + 512 * 1024);         // 512 KB
    u16* WTq = (u16*)(ws + 1 * MB);                  // 4 x 128 KB (contiguous)
    u16* WTk = WTq + 65536;
    u16* WTv = WTk + 65536;
    u16* WoT = WTv + 65536;
    u16* qr   = (u16*)(ws + 2 * MB);                 // 32 MB each
    u16* kr   = (u16*)(ws + 2 * MB + 32 * MB);
    u16* v    = (u16*)(ws + 2 * MB + 64 * MB);
    u16* lepe = (u16*)(ws + 2 * MB + 96 * MB);
    u16* xT   = (u16*)(ws + 2 * MB + 128 * MB);      // dead after k_qkv_fused
    u16* v5   = xT;                                   // reuse: (b,w,n,h,d)
    u16* attn = v;                                    // reuse (attn + lepe)

    k_tables<<<dim3(512), dim3(256), 0, stream>>>(sinT, cosT);
    k_prep_w<<<dim3(8, 8, 4), dim3(256), 0, stream>>>(Wq, Wk, Wv, Wo, WTq, WTk, WTv, WoT);
    k_prep_x<<<dim3(128, 8, 16), dim3(256), 0, stream>>>(x, xT);
    k_qkv_fused<<<dim3(512), dim3(512), 0, stream>>>(
        xT, WTq, bq, bk, bv, sinT, cosT, qr, kr, v);
    k_lepe<<<dim3(64, 4, 16), dim3(256), 0, stream>>>(v, dwk, dwb, lepe);
    k_attn_mfma<0><<<dim3(1024), dim3(256), 0, stream>>>(qr, kr, v, nullptr, v5);
    k_attn_mfma<1><<<dim3(1024), dim3(256), 0, stream>>>(qr, kr, v5, lepe, attn);
    k_proj_fused<<<dim3(512), dim3(512), 0, stream>>>(WoT, attn, bo, y);
}

// Round 6
// 212.952 us; speedup vs baseline: 3.8127x; 1.2798x over previous
//
#include <hip/hip_runtime.h>
#include <hip/hip_bf16.h>

typedef unsigned short u16;
typedef unsigned int   u32;
typedef __attribute__((ext_vector_type(8))) short bf16x8;
typedef __attribute__((ext_vector_type(4))) float f32x4;

// ---------- bf16 helpers ----------
__device__ __forceinline__ float bf2f(u16 u) {
    union { u32 i; float f; } x; x.i = ((u32)u) << 16; return x.f;
}
__device__ __forceinline__ u16 f2bf(float f) {
    union { float f; u32 i; } x; x.f = f;
    u32 i = x.i;
    u32 r = (i + 0x7fffu + ((i >> 16) & 1u)) >> 16;  // RNE
    return (u16)r;
}

// =============== 1. sin/cos tables [4096][32] fp32 (pairs share angle) ======
__global__ void k_tables(float* __restrict__ sinT, float* __restrict__ cosT) {
    int id = blockIdx.x * 256 + threadIdx.x;   // 0..131071 = t*32+i
    int t = id >> 5, i = id & 31;
    double ang = pow(10000.0, -(double)i / 31.0);
    double a = (double)t * ang;
    sinT[id] = (float)sin(a);
    cosT[id] = (float)cos(a);
}

// =============== 2a. weight transpose+convert: WT[out][in] = W[in][out] =====
__global__ __launch_bounds__(256) void k_prep_w(
    const float* __restrict__ Wq, const float* __restrict__ Wk,
    const float* __restrict__ Wv, const float* __restrict__ Wo,
    u16* __restrict__ WTq, u16* __restrict__ WTk,
    u16* __restrict__ WTv, u16* __restrict__ WoT)
{
    __shared__ float T[32][33];
    int z = blockIdx.z;
    const float* W = (z == 0) ? Wq : (z == 1) ? Wk : (z == 2) ? Wv : Wo;
    u16* WT        = (z == 0) ? WTq : (z == 1) ? WTk : (z == 2) ? WTv : WoT;
    int n0 = blockIdx.x * 32, k0 = blockIdx.y * 32;
    int tx = threadIdx.x & 31, ty = threadIdx.x >> 5;   // ty 0..7
#pragma unroll
    for (int i = 0; i < 4; i++)
        T[ty * 4 + i][tx] = W[(k0 + ty * 4 + i) * 256 + n0 + tx];
    __syncthreads();
#pragma unroll
    for (int i = 0; i < 4; i++)
        WT[(n0 + ty * 4 + i) * 256 + k0 + tx] = f2bf(T[tx][ty * 4 + i]);
}

// =============== 2b. x transpose+convert: xT[b*4096+s][c] bf16 ==============
__global__ __launch_bounds__(256) void k_prep_x(
    const float* __restrict__ x, u16* __restrict__ xT)
{
    __shared__ float T[32][33];
    int b = blockIdx.z, c0 = blockIdx.y * 32, s0 = blockIdx.x * 32;
    int tx = threadIdx.x & 31, ty = threadIdx.x >> 5;
#pragma unroll
    for (int i = 0; i < 4; i++)
        T[ty * 4 + i][tx] = x[((size_t)(b * 256 + c0 + ty * 4 + i)) * 4096 + s0 + tx];
    __syncthreads();
#pragma unroll
    for (int i = 0; i < 4; i++)
        xT[((size_t)(b * 4096 + s0 + ty * 4 + i)) * 256 + c0 + tx] = f2bf(T[tx][ty * 4 + i]);
}

// =============== 3. fused QKV: A-tile resident, loop 3 mats =================
__global__ __launch_bounds__(512, 1) void k_qkv_fused(
    const u16* __restrict__ xT, const u16* __restrict__ WTall,
    const float* __restrict__ bq, const float* __restrict__ bk,
    const float* __restrict__ bv,
    const float* __restrict__ sinT, const float* __restrict__ cosT,
    u16* __restrict__ qr, u16* __restrict__ kr, u16* __restrict__ vO)
{
    __shared__ alignas(16) u16 Alds[128 * 256];   // 64 KB
    __shared__ alignas(16) u16 Blds[256 * 64];    // 32 KB
    __shared__ float2 SL[128 * 32];               // 32 KB (cos, sin)

    const int tid = threadIdx.x;
    const int t0 = blockIdx.x * 128;

    const int ar = tid >> 5, ac = tid & 31;   // A staging
    const int br = tid >> 3, bc = tid & 7;    // B staging

    bf16x8 areg[8], breg[4];
#pragma unroll
    for (int p = 0; p < 8; ++p)
        areg[p] = *(const bf16x8*)(xT + (size_t)(t0 + p * 16 + ar) * 256 + ac * 8);
#pragma unroll
    for (int p = 0; p < 4; ++p)
        breg[p] = *(const bf16x8*)(WTall + (size_t)(p * 64 + br) * 256 + bc * 8);

#pragma unroll
    for (int p = 0; p < 8; ++p) {
        int r = p * 16 + ar;
        *(bf16x8*)(Alds + r * 256 + (ac ^ (r & 7)) * 8) = areg[p];
    }
    {
        const int sb = t0 & 4095;
#pragma unroll
        for (int p = 0; p < 8; ++p) {
            int idx = p * 512 + tid;            // 0..4095 = sl*32 + ii
            int sl = idx >> 5, ii = idx & 31;
            SL[idx] = make_float2(cosT[(sb + sl) * 32 + ii], sinT[(sb + sl) * 32 + ii]);
        }
    }

    const int lane = tid & 63, w = tid >> 6;
    const int wr = w >> 2, wc = w & 3;
    const int l15 = lane & 15, l4 = lane >> 4, l7 = lane & 7;

#pragma unroll
    for (int mat = 0; mat < 3; ++mat) {
        f32x4 acc[4][4];
#pragma unroll
        for (int mi = 0; mi < 4; ++mi)
#pragma unroll
            for (int ni = 0; ni < 4; ++ni) acc[mi][ni] = (f32x4)0.f;

#pragma unroll
        for (int ks = 0; ks < 4; ++ks) {
            const int s = mat * 4 + ks;
            __syncthreads();                       // readers of prev Blds done
#pragma unroll
            for (int p = 0; p < 4; ++p) {
                int r = p * 64 + br;
                *(bf16x8*)(Blds + r * 64 + (bc ^ (r & 7)) * 8) = breg[p];
            }
            __syncthreads();                       // Blds ready
            if (s < 11) {                          // issue next loads under MFMA
                const int s2 = s + 1;
                const int mat2 = s2 >> 2, ks2 = s2 & 3;
#pragma unroll
                for (int p = 0; p < 4; ++p)
                    breg[p] = *(const bf16x8*)(WTall + (size_t)mat2 * 65536 +
                                (size_t)(p * 64 + br) * 256 + ks2 * 64 + bc * 8);
            }
#pragma unroll
            for (int kk = 0; kk < 2; ++kk) {
                bf16x8 af[4], bfr[4];
#pragma unroll
                for (int mi = 0; mi < 4; ++mi) {
                    int r = wr * 64 + mi * 16 + l15;
                    af[mi] = *(const bf16x8*)(Alds + r * 256 + (ks * 8 + ((kk * 4 + l4) ^ l7)) * 8);
                }
#pragma unroll
                for (int ni = 0; ni < 4; ++ni) {
                    int r = wc * 64 + ni * 16 + l15;
                    bfr[ni] = *(const bf16x8*)(Blds + r * 64 + ((kk * 4 + l4) ^ l7) * 8);
                }
#pragma unroll
                for (int mi = 0; mi < 4; ++mi)
#pragma unroll
                    for (int ni = 0; ni < 4; ++ni)
                        acc[mi][ni] = __builtin_amdgcn_mfma_f32_16x16x32_bf16(
                            af[mi], bfr[ni], acc[mi][ni], 0, 0, 0);
            }
        }

        const float* bias = (mat == 0) ? bq : (mat == 1) ? bk : bv;
        u16* out          = (mat == 0) ? qr : (mat == 1) ? kr : vO;
        const float kscale = (mat == 1) ? 0.125f : 1.0f;
        float bcol[4]; int ip[4];
#pragma unroll
        for (int ni = 0; ni < 4; ++ni) {
            bcol[ni] = bias[wc * 64 + ni * 16 + l15];
            ip[ni] = (ni * 16 + l15) >> 1;
        }
#pragma unroll
        for (int mi = 0; mi < 4; ++mi) {
#pragma unroll
            for (int rg = 0; rg < 4; ++rg) {
                const int sl = wr * 64 + mi * 16 + l4 * 4 + rg;
                size_t trow = (size_t)(t0 + sl) * 256;
#pragma unroll
                for (int ni = 0; ni < 4; ++ni) {
                    float val = acc[mi][ni][rg] + bcol[ni];
                    float res;
                    if (mat != 2) {
                        val *= kscale;
                        float prt = __shfl_xor(val, 1);
                        float2 cs = SL[sl * 32 + ip[ni]];
                        res = (lane & 1) ? fmaf(val, cs.x,  prt * cs.y)
                                         : fmaf(val, cs.x, -prt * cs.y);
                    } else {
                        res = val;
                    }
                    float res2 = __shfl_xor(res, 1);
                    if (!(lane & 1)) {
                        u32 pk;
                        asm("v_cvt_pk_bf16_f32 %0, %1, %2" : "=v"(pk) : "v"(res), "v"(res2));
                        int o = wc * 64 + ni * 16 + l15;
                        *(u32*)(out + trow + o) = pk;
                    }
                }
            }
        }
    }
}

// =============== 4. LEPE: 5x5 depthwise conv, register row-caching ==========
// grid (64 spatial tiles, 4 chan groups, 16 batch), block 256.
// Halo staged bf16 (18 KB); each thread: c = tid&63, 2 out rows x 8 cols.
// Per input row: 12 LDS reads -> regs -> up to 80 FMAs. 72 reads total.
__global__ __launch_bounds__(256) void k_lepe(
    const u16* __restrict__ v, const float* __restrict__ dwk,
    const float* __restrict__ dwb, u16* __restrict__ lepe)
{
    __shared__ u16 VhU[12 * 12 * 64];   // [pos][c] bf16 raw, 18 KB
    __shared__ float Kl[25][64];        // 6.4 KB
    const int b = blockIdx.z, cg = blockIdx.y * 64;
    const int ty0 = (blockIdx.x >> 3) * 8, tx0 = (blockIdx.x & 7) * 8;
    const int tid = threadIdx.x;

    for (int idx = tid; idx < 1600; idx += 256) {
        int tap = idx >> 6, c = idx & 63;
        Kl[tap][c] = dwk[tap * 256 + cg + c];
    }
    // ---- stage 12x12 halo as ushort4 chunks: 2304 chunks, 9 passes
#pragma unroll
    for (int p = 0; p < 9; ++p) {
        int idx = p * 256 + tid;            // 0..2303
        int ch = idx & 15, pos = idx >> 4;  // chunk 0..15, pos 0..143
        int py = pos / 12, px = pos - py * 12;
        int gy = ty0 + py - 2, gx = tx0 + px - 2;
        ushort4 val = make_ushort4(0, 0, 0, 0);
        if (gy >= 0 && gy < 64 && gx >= 0 && gx < 64)
            val = *(const ushort4*)(v + (size_t)(b * 4096 + gy * 64 + gx) * 256 + cg + ch * 4);
        *(ushort4*)(VhU + pos * 64 + ch * 4) = val;
    }
    __syncthreads();

    const int c = tid & 63, pg = tid >> 6;
    float kreg[25];
#pragma unroll
    for (int t = 0; t < 25; t++) kreg[t] = Kl[t][c];
    const float bias = dwb[cg + c];

    float acc[2][8];
#pragma unroll
    for (int t = 0; t < 2; ++t)
#pragma unroll
        for (int ox = 0; ox < 8; ++ox) acc[t][ox] = bias;

#pragma unroll
    for (int rr = 0; rr < 6; ++rr) {
        const int r = pg * 2 + rr;          // input halo row
        float rv[12];
#pragma unroll
        for (int px = 0; px < 12; ++px)
            rv[px] = bf2f(VhU[(r * 12 + px) * 64 + c]);
        if (rr <= 4) {                      // contributes to out row pg*2 (t=0)
            const int dy = rr;
#pragma unroll
            for (int ox = 0; ox < 8; ++ox)
#pragma unroll
                for (int dx = 0; dx < 5; ++dx)
                    acc[0][ox] = fmaf(rv[ox + dx], kreg[dy * 5 + dx], acc[0][ox]);
        }
        if (rr >= 1) {                      // contributes to out row pg*2+1 (t=1)
            const int dy = rr - 1;
#pragma unroll
            for (int ox = 0; ox < 8; ++ox)
#pragma unroll
                for (int dx = 0; dx < 5; ++dx)
                    acc[1][ox] = fmaf(rv[ox + dx], kreg[dy * 5 + dx], acc[1][ox]);
        }
    }

#pragma unroll
    for (int t = 0; t < 2; ++t) {
        const int oy = pg * 2 + t;
#pragma unroll
        for (int ox = 0; ox < 8; ++ox)
            lepe[(size_t)(b * 4096 + (ty0 + oy) * 64 + tx0 + ox) * 256 + cg + c] =
                f2bf(acc[t][ox]);
    }
}

// =============== 5/6. Axial attention, per-wave MFMA flash ==================
template <int AXIS>
__global__ __launch_bounds__(256) void k_attn_mfma(
    const u16* __restrict__ qr, const u16* __restrict__ kr,
    const u16* __restrict__ vsrc, const u16* __restrict__ lepeP,
    u16* __restrict__ outb)
{
    __shared__ u16 VT[4][64 * 72];   // V^T tile [d][k], pitch 72, swizzled
    __shared__ u16 PL[4][64 * 72];   // P tile [q][k], pitch 72; reused for O

    const int tid = threadIdx.x;
    const int w = tid >> 6, lane = tid & 63;
    const int l15 = lane & 15, l4 = lane >> 4;
    const int wid = blockIdx.x * 4 + w;
    const int b = wid >> 8, xy = (wid >> 2) & 63, n = wid & 3;

    size_t qkbase, vbase; int qkstride, vstride;
    if (AXIS == 0) {
        qkbase = ((size_t)(b * 4096 + xy * 64)) * 256 + n * 64;
        qkstride = 256;
        vbase = qkbase; vstride = 256;
    } else {
        qkbase = ((size_t)(b * 4096 + xy)) * 256 + n * 64;
        qkstride = 64 * 256;
        vbase = ((size_t)((b * 64 + xy) * 4 + n)) * 4096;
        vstride = 64;
    }

    u16* VTl = &VT[w][0];
    u16* PLl = &PL[w][0];

    bf16x8 vld[8];
    const int vrow = lane >> 3, vchunk = lane & 7;
#pragma unroll
    for (int it = 0; it < 8; ++it)
        vld[it] = *(const bf16x8*)(vsrc + vbase + (size_t)(it * 8 + vrow) * vstride + vchunk * 8);

    bf16x8 ka[4][2], qb[4][2];
#pragma unroll
    for (int t = 0; t < 4; ++t)
#pragma unroll
        for (int ks = 0; ks < 2; ++ks) {
            ka[t][ks] = *(const bf16x8*)(kr + qkbase + (size_t)(t * 16 + l15) * qkstride + ks * 32 + l4 * 8);
            qb[t][ks] = *(const bf16x8*)(qr + qkbase + (size_t)(t * 16 + l15) * qkstride + ks * 32 + l4 * 8);
        }

    f32x4 sacc[4][4];   // [kt][qt]
#pragma unroll
    for (int kt = 0; kt < 4; ++kt)
#pragma unroll
        for (int qt = 0; qt < 4; ++qt) sacc[kt][qt] = (f32x4)0.f;
#pragma unroll
    for (int ks = 0; ks < 2; ++ks)
#pragma unroll
        for (int kt = 0; kt < 4; ++kt)
#pragma unroll
            for (int qt = 0; qt < 4; ++qt)
                sacc[kt][qt] = __builtin_amdgcn_mfma_f32_16x16x32_bf16(
                    ka[kt][ks], qb[qt][ks], sacc[kt][qt], 0, 0, 0);

#pragma unroll
    for (int it = 0; it < 8; ++it) {
        int gp = ((it ^ vchunk) << 3) + vrow;
#pragma unroll
        for (int j = 0; j < 8; ++j) {
            int d = vchunk * 8 + j;
            VTl[d * 72 + gp] = (u16)vld[it][j];
        }
    }

    const float decay = logf(1.0f - exp2f(-(1.0f + 0.75f * (float)n)));
#pragma unroll
    for (int qt = 0; qt < 4; ++qt) {
        const int qq = qt * 16 + l15;
        float lsum = 0.f;
#pragma unroll
        for (int kt = 0; kt < 4; ++kt) {
            const int kb = kt * 16 + l4 * 4;
#pragma unroll
            for (int rr = 0; rr < 4; ++rr) {
                float s = sacc[kt][qt][rr] + fabsf((float)(qq - kb - rr)) * decay;
                s = __expf(s);
                sacc[kt][qt][rr] = s;
                lsum += s;
            }
        }
        lsum += __shfl_xor(lsum, 16);
        lsum += __shfl_xor(lsum, 32);
        const float rinv = 1.0f / lsum;
#pragma unroll
        for (int kt = 0; kt < 4; ++kt) {
            float e0 = sacc[kt][qt][0] * rinv, e1 = sacc[kt][qt][1] * rinv;
            float e2 = sacc[kt][qt][2] * rinv, e3 = sacc[kt][qt][3] * rinv;
            u32 p0, p1;
            asm("v_cvt_pk_bf16_f32 %0, %1, %2" : "=v"(p0) : "v"(e0), "v"(e1));
            asm("v_cvt_pk_bf16_f32 %0, %1, %2" : "=v"(p1) : "v"(e2), "v"(e3));
            uint2 pp; pp.x = p0; pp.y = p1;
            *(uint2*)(PLl + (qt * 16 + l15) * 72 + kt * 16 + l4 * 4) = pp;
        }
    }

    __builtin_amdgcn_s_waitcnt(0xC07F);
    bf16x8 pa[4][2], vb[4][2];
#pragma unroll
    for (int qt = 0; qt < 4; ++qt)
#pragma unroll
        for (int ks = 0; ks < 2; ++ks)
            pa[qt][ks] = *(const bf16x8*)(PLl + (qt * 16 + l15) * 72 + ks * 32 + l4 * 8);
#pragma unroll
    for (int dt = 0; dt < 4; ++dt)
#pragma unroll
        for (int ks = 0; ks < 2; ++ks) {
            int d = dt * 16 + l15;
            int g = (ks * 4 + l4) ^ (d >> 3);
            vb[dt][ks] = *(const bf16x8*)(VTl + d * 72 + g * 8);
        }

    f32x4 oacc[4][4];   // [qt][dt]
#pragma unroll
    for (int qt = 0; qt < 4; ++qt)
#pragma unroll
        for (int dt = 0; dt < 4; ++dt) oacc[qt][dt] = (f32x4)0.f;
#pragma unroll
    for (int ks = 0; ks < 2; ++ks)
#pragma unroll
        for (int qt = 0; qt < 4; ++qt)
#pragma unroll
            for (int dt = 0; dt < 4; ++dt)
                oacc[qt][dt] = __builtin_amdgcn_mfma_f32_16x16x32_bf16(
                    pa[qt][ks], vb[dt][ks], oacc[qt][dt], 0, 0, 0);

#pragma unroll
    for (int qt = 0; qt < 4; ++qt)
#pragma unroll
        for (int dt = 0; dt < 4; ++dt)
#pragma unroll
            for (int rr = 0; rr < 4; ++rr)
                PLl[(qt * 16 + l4 * 4 + rr) * 72 + dt * 16 + l15] = f2bf(oacc[qt][dt][rr]);
    __builtin_amdgcn_s_waitcnt(0xC07F);

    size_t orow;
    if (AXIS == 0) orow = ((size_t)((b * 64 + lane) * 4 + n)) * 4096 + xy * 64;
    else           orow = ((size_t)(b * 4096 + lane * 64 + xy)) * 256 + n * 64;
#pragma unroll
    for (int c = 0; c < 8; ++c) {
        bf16x8 o8 = *(const bf16x8*)(PLl + lane * 72 + c * 8);
        if (AXIS == 1) {
            bf16x8 lp = *(const bf16x8*)(lepeP + orow + c * 8);
            u16 hv[8];
#pragma unroll
            for (int j = 0; j < 8; ++j)
                hv[j] = f2bf(bf2f((u16)o8[j]) + bf2f((u16)lp[j]));
            o8 = *(bf16x8*)hv;
        }
        *(bf16x8*)(outb + orow + c * 8) = o8;
    }
}

// =============== 7. fused output projection =================================
__global__ __launch_bounds__(512, 1) void k_proj_fused(
    const u16* __restrict__ WoT, const u16* __restrict__ attnL,
    const float* __restrict__ bo, float* __restrict__ y)
{
    __shared__ alignas(16) u16 Alds[128 * 256];   // 64 KB
    __shared__ alignas(16) u16 Blds[256 * 64];    // 32 KB

    const int tid = threadIdx.x;
    const int bid = blockIdx.x;                   // 512 blocks
    const int xcd = bid & 7, slot = bid >> 3;
    const int tt = xcd * 32 + (slot >> 1);
    const int oh = slot & 1;
    const int t0 = tt * 256;
    const int o0 = oh * 128;

    const int ar = tid >> 5, ac = tid & 31;
    const int br = tid >> 3, bc = tid & 7;

    bf16x8 areg[8], breg[4];
#pragma unroll
    for (int p = 0; p < 8; ++p)
        areg[p] = *(const bf16x8*)(WoT + (size_t)(o0 + p * 16 + ar) * 256 + ac * 8);
#pragma unroll
    for (int p = 0; p < 4; ++p)
        breg[p] = *(const bf16x8*)(attnL + (size_t)(t0 + p * 64 + br) * 256 + bc * 8);

#pragma unroll
    for (int p = 0; p < 8; ++p) {
        int r = p * 16 + ar;
        *(bf16x8*)(Alds + r * 256 + (ac ^ (r & 7)) * 8) = areg[p];
    }

    const int lane = tid & 63, w = tid >> 6;
    const int wr = w >> 2, wc = w & 3;
    const int l15 = lane & 15, l4 = lane >> 4, l7 = lane & 7;

    f32x4 acc[4][4];
#pragma unroll
    for (int mi = 0; mi < 4; ++mi)
#pragma unroll
        for (int ni = 0; ni < 4; ++ni) acc[mi][ni] = (f32x4)0.f;

#pragma unroll
    for (int ks = 0; ks < 4; ++ks) {
        __syncthreads();
#pragma unroll
        for (int p = 0; p < 4; ++p) {
            int r = p * 64 + br;
            *(bf16x8*)(Blds + r * 64 + (bc ^ (r & 7)) * 8) = breg[p];
        }
        __syncthreads();
        if (ks < 3) {                              // issue next loads under MFMA
#pragma unroll
            for (int p = 0; p < 4; ++p)
                breg[p] = *(const bf16x8*)(attnL + (size_t)(t0 + p * 64 + br) * 256 + (ks + 1) * 64 + bc * 8);
        }
#pragma unroll
        for (int kk = 0; kk < 2; ++kk) {
            bf16x8 af[4], bfr[4];
#pragma unroll
            for (int mi = 0; mi < 4; ++mi) {
                int r = wr * 64 + mi * 16 + l15;
                af[mi] = *(const bf16x8*)(Alds + r * 256 + (ks * 8 + ((kk * 4 + l4) ^ l7)) * 8);
            }
#pragma unroll
            for (int ni = 0; ni < 4; ++ni) {
                int r = wc * 64 + ni * 16 + l15;
                bfr[ni] = *(const bf16x8*)(Blds + r * 64 + ((kk * 4 + l4) ^ l7) * 8);
            }
#pragma unroll
            for (int mi = 0; mi < 4; ++mi)
#pragma unroll
                for (int ni = 0; ni < 4; ++ni)
                    acc[mi][ni] = __builtin_amdgcn_mfma_f32_16x16x32_bf16(
                        af[mi], bfr[ni], acc[mi][ni], 0, 0, 0);
        }
    }

    const int b = t0 >> 12, sb = t0 & 4095;
#pragma unroll
    for (int mi = 0; mi < 4; ++mi) {
#pragma unroll
        for (int rg = 0; rg < 4; ++rg) {
            int o = o0 + wr * 64 + mi * 16 + l4 * 4 + rg;
            float bb = bo[o];
            float* yrow = y + ((size_t)(b * 256 + o)) * 4096 + sb + wc * 64;
#pragma unroll
            for (int ni = 0; ni < 4; ++ni)
                yrow[ni * 16 + l15] = acc[mi][ni][rg] + bb;
        }
    }
}

// ============================ launcher ======================================
extern "C" void kernel_launch(void* const* d_in, const int* in_sizes, int n_in,
                              void* d_out, int out_size, void* d_ws, size_t ws_size,
                              hipStream_t stream)
{
    const float* x   = (const float*)d_in[0];
    const float* Wq  = (const float*)d_in[1];
    const float* bq  = (const float*)d_in[2];
    const float* Wk  = (const float*)d_in[3];
    const float* bk  = (const float*)d_in[4];
    const float* Wv  = (const float*)d_in[5];
    const float* bv  = (const float*)d_in[6];
    const float* dwk = (const float*)d_in[7];
    const float* dwb = (const float*)d_in[8];
    const float* Wo  = (const float*)d_in[9];
    const float* bo  = (const float*)d_in[10];
    float* y = (float*)d_out;

    char* ws = (char*)d_ws;
    const size_t MB = 1024 * 1024;
    float* sinT = (float*)(ws);                      // 512 KB
    float* cosT = (float*)(ws + 512 * 1024);         // 512 KB
    u16* WTq = (u16*)(ws + 1 * MB);                  // 4 x 128 KB (contiguous)
    u16* WTk = WTq + 65536;
    u16* WTv = WTk + 65536;
    u16* WoT = WTv + 65536;
    u16* qr   = (u16*)(ws + 2 * MB);                 // 32 MB each
    u16* kr   = (u16*)(ws + 2 * MB + 32 * MB);
    u16* v    = (u16*)(ws + 2 * MB + 64 * MB);
    u16* lepe = (u16*)(ws + 2 * MB + 96 * MB);
    u16* xT   = (u16*)(ws + 2 * MB + 128 * MB);      // dead after k_qkv_fused
    u16* v5   = xT;                                   // reuse: (b,w,n,h,d)
    u16* attn = v;                                    // reuse (attn + lepe)

    k_tables<<<dim3(512), dim3(256), 0, stream>>>(sinT, cosT);
    k_prep_w<<<dim3(8, 8, 4), dim3(256), 0, stream>>>(Wq, Wk, Wv, Wo, WTq, WTk, WTv, WoT);
    k_prep_x<<<dim3(128, 8, 16), dim3(256), 0, stream>>>(x, xT);
    k_qkv_fused<<<dim3(512), dim3(512), 0, stream>>>(
        xT, WTq, bq, bk, bv, sinT, cosT, qr, kr, v);
    k_lepe<<<dim3(64, 4, 16), dim3(256), 0, stream>>>(v, dwk, dwb, lepe);
    k_attn_mfma<0><<<dim3(1024), dim3(256), 0, stream>>>(qr, kr, v, nullptr, v5);
    k_attn_mfma<1><<<dim3(1024), dim3(256), 0, stream>>>(qr, kr, v5, lepe, attn);
    k_proj_fused<<<dim3(512), dim3(512), 0, stream>>>(WoT, attn, bo, y);
}